// Round 1
// baseline (1751.962 us; speedup 1.0000x reference)
//
#include <hip/hip_runtime.h>
#include <hip/hip_bf16.h>

// EnhancedGNNEncoder: N nodes, E edges, C=14 channels, D=3, A=16, F=H=RNF=128.
// Round 1: correctness-first fp32 vector implementation.
//   memset -> k_prep -> k_radial -> k_edge -> k_node -> k_xnew
// GEMMs: register tile 2 rows x 4 cols per thread, float4 weight loads.
// radial features cached in ws as bf16 (51 MB) to keep ws usage ~65 MB.

#define TE 16   // edges per block
#define TN 16   // nodes per block

__device__ __forceinline__ float siluf(float v) { return v / (1.f + __expf(-v)); }
__device__ __forceinline__ float sigmf(float v) { return 1.f / (1.f + __expf(-v)); }

// acc[ee][j] += sum_{k<128} src[g*2+ee][k] * W[k*128 + o4 + j]
__device__ __forceinline__ void gemm_acc(const float (*__restrict__ src)[128],
                                         const float* __restrict__ W,
                                         int o4, int g, float acc[2][4]) {
  for (int k = 0; k < 128; k += 4) {
    float4 w0 = *(const float4*)&W[(k + 0) * 128 + o4];
    float4 w1 = *(const float4*)&W[(k + 1) * 128 + o4];
    float4 w2 = *(const float4*)&W[(k + 2) * 128 + o4];
    float4 w3 = *(const float4*)&W[(k + 3) * 128 + o4];
#pragma unroll
    for (int ee = 0; ee < 2; ee++) {
      const float4 r = *(const float4*)&src[g * 2 + ee][k];
      acc[ee][0] = fmaf(r.x, w0.x, fmaf(r.y, w1.x, fmaf(r.z, w2.x, fmaf(r.w, w3.x, acc[ee][0]))));
      acc[ee][1] = fmaf(r.x, w0.y, fmaf(r.y, w1.y, fmaf(r.z, w2.y, fmaf(r.w, w3.y, acc[ee][1]))));
      acc[ee][2] = fmaf(r.x, w0.z, fmaf(r.y, w1.z, fmaf(r.z, w2.z, fmaf(r.w, w3.z, acc[ee][2]))));
      acc[ee][3] = fmaf(r.x, w0.w, fmaf(r.y, w1.w, fmaf(r.z, w2.w, fmaf(r.w, w3.w, acc[ee][3]))));
    }
  }
}

// ---- per-node prep: channel_sum + masked-mean pooled coords ----
__global__ __launch_bounds__(256) void k_prep(const float* __restrict__ x,
                                              const float* __restrict__ cw,
                                              float* __restrict__ pooled_x,
                                              int* __restrict__ chsum, int Nn) {
  int n = blockIdx.x * 256 + threadIdx.x;
  if (n >= Nn) return;
  int cnt = 0;
  float sx = 0.f, sy = 0.f, sz = 0.f;
#pragma unroll
  for (int c = 0; c < 14; c++) {
    float w = cw[n * 14 + c];
    if (w != 0.f) {
      cnt++;
      sx += x[n * 42 + c * 3 + 0];
      sy += x[n * 42 + c * 3 + 1];
      sz += x[n * 42 + c * 3 + 2];
    }
  }
  chsum[n] = cnt;
  float inv = 1.f / (float)(cnt > 0 ? cnt : 1);
  pooled_x[n * 3 + 0] = sx * inv;
  pooled_x[n * 3 + 1] = sy * inv;
  pooled_x[n * 3 + 2] = sz * inv;
}

// ---- radial: coord2radial einsum + rad_w GEMM; also edge-count atomics ----
__global__ __launch_bounds__(256) void k_radial(
    const float* __restrict__ x, const float* __restrict__ attr, const float* __restrict__ cw,
    const int* __restrict__ row, const int* __restrict__ col,
    const float* __restrict__ rad_w, const float* __restrict__ rad_b,
    __hip_bfloat16* __restrict__ radf,
    unsigned* __restrict__ cnt_row, unsigned* __restrict__ cnt_col, int Ee) {
  __shared__ float s_xr[TE][14][3], s_xc[TE][14][3];
  __shared__ float s_cwr[TE][14], s_cwc[TE][14];
  __shared__ __hip_bfloat16 s_ar[TE][14][16], s_ac[TE][14][16];
  __shared__ __hip_bfloat16 s_msg[TE][14][14];
  __shared__ __hip_bfloat16 s_m1[TE][14][16];
  __shared__ float s_rad[TE][256];
  __shared__ float s_red[TE][16];
  __shared__ float s_rn[TE];
  __shared__ int s_row[TE], s_col[TE];

  const int t = threadIdx.x;
  const int e0 = blockIdx.x * TE;
  const int ne = min(TE, Ee - e0);

  if (t < TE) {
    int e = e0 + min(t, ne - 1);
    s_row[t] = row[e];
    s_col[t] = col[e];
    if (t < ne) {
      atomicAdd(&cnt_row[s_row[t]], 1u);
      atomicAdd(&cnt_col[s_col[t]], 1u);
    }
  }
  __syncthreads();
  for (int i = t; i < TE * 42; i += 256) {
    int e = i / 42, r = i % 42;
    s_xr[e][r / 3][r % 3] = x[(size_t)s_row[e] * 42 + r];
    s_xc[e][r / 3][r % 3] = x[(size_t)s_col[e] * 42 + r];
  }
  for (int i = t; i < TE * 14; i += 256) {
    int e = i / 14, c = i % 14;
    s_cwr[e][c] = cw[(size_t)s_row[e] * 14 + c];
    s_cwc[e][c] = cw[(size_t)s_col[e] * 14 + c];
  }
  for (int i = t; i < TE * 224; i += 256) {
    int e = i / 224, r = i % 224;
    s_ar[e][r / 16][r % 16] = __float2bfloat16(attr[(size_t)s_row[e] * 224 + r]);
    s_ac[e][r / 16][r % 16] = __float2bfloat16(attr[(size_t)s_col[e] * 224 + r]);
  }
  __syncthreads();
  // msg[i][j] = ||xr_i - xc_j|| * cwr_i * cwc_j
  for (int i = t; i < TE * 196; i += 256) {
    int e = i / 196, r = i % 196, ci = r / 14, cj = r % 14;
    float dx = s_xr[e][ci][0] - s_xc[e][cj][0];
    float dy = s_xr[e][ci][1] - s_xc[e][cj][1];
    float dz = s_xr[e][ci][2] - s_xc[e][cj][2];
    float d = sqrtf(dx * dx + dy * dy + dz * dz);
    s_msg[e][ci][cj] = __float2bfloat16(d * s_cwr[e][ci] * s_cwc[e][cj]);
  }
  __syncthreads();
  // M1[c][b] = sum_j msg[c][j] * attrC[j][b]
  for (int i = t; i < TE * 224; i += 256) {
    int e = i / 224, r = i % 224, c = r / 16, b = r % 16;
    float acc = 0.f;
#pragma unroll
    for (int j = 0; j < 14; j++)
      acc += __bfloat162float(s_msg[e][c][j]) * __bfloat162float(s_ac[e][j][b]);
    s_m1[e][c][b] = __float2bfloat16(acc);
  }
  __syncthreads();
  // radial[a*16+b] = sum_c attrR[c][a] * M1[c][b]  (+ sumsq for the norm)
  {
    int e = t >> 4, b = t & 15;
    float ss = 0.f;
#pragma unroll
    for (int a = 0; a < 16; a++) {
      float acc = 0.f;
#pragma unroll
      for (int c = 0; c < 14; c++)
        acc += __bfloat162float(s_ar[e][c][a]) * __bfloat162float(s_m1[e][c][b]);
      s_rad[e][a * 16 + b] = acc;
      ss += acc * acc;
    }
    s_red[e][b] = ss;
  }
  __syncthreads();
  if (t < TE) {
    float s = 0.f;
#pragma unroll
    for (int i = 0; i < 16; i++) s += s_red[t][i];
    s_rn[t] = sqrtf(s) + 1.0f;
  }
  __syncthreads();
  // radf = (radial @ rad_w + rad_b) / rn
  {
    const int o4 = (t & 31) * 4, g = t >> 5;
    float acc[2][4] = {};
    for (int k = 0; k < 256; k += 4) {
      float4 w0 = *(const float4*)&rad_w[(k + 0) * 128 + o4];
      float4 w1 = *(const float4*)&rad_w[(k + 1) * 128 + o4];
      float4 w2 = *(const float4*)&rad_w[(k + 2) * 128 + o4];
      float4 w3 = *(const float4*)&rad_w[(k + 3) * 128 + o4];
#pragma unroll
      for (int ee = 0; ee < 2; ee++) {
        const float4 r = *(const float4*)&s_rad[g * 2 + ee][k];
        acc[ee][0] = fmaf(r.x, w0.x, fmaf(r.y, w1.x, fmaf(r.z, w2.x, fmaf(r.w, w3.x, acc[ee][0]))));
        acc[ee][1] = fmaf(r.x, w0.y, fmaf(r.y, w1.y, fmaf(r.z, w2.y, fmaf(r.w, w3.y, acc[ee][1]))));
        acc[ee][2] = fmaf(r.x, w0.z, fmaf(r.y, w1.z, fmaf(r.z, w2.z, fmaf(r.w, w3.z, acc[ee][2]))));
        acc[ee][3] = fmaf(r.x, w0.w, fmaf(r.y, w1.w, fmaf(r.z, w2.w, fmaf(r.w, w3.w, acc[ee][3]))));
      }
    }
    float4 b4 = *(const float4*)&rad_b[o4];
#pragma unroll
    for (int ee = 0; ee < 2; ee++) {
      int e = g * 2 + ee;
      if (e < ne) {
        float inv = 1.f / s_rn[e];
        size_t idx = (size_t)(e0 + e) * 128 + o4;
        radf[idx + 0] = __float2bfloat16((acc[ee][0] + b4.x) * inv);
        radf[idx + 1] = __float2bfloat16((acc[ee][1] + b4.y) * inv);
        radf[idx + 2] = __float2bfloat16((acc[ee][2] + b4.z) * inv);
        radf[idx + 3] = __float2bfloat16((acc[ee][3] + b4.w) * inv);
      }
    }
  }
}

// ---- fused edge MLP + gate + coord MLP + RollerPooling + scatters ----
__global__ __launch_bounds__(256) void k_edge(
    const float* __restrict__ h, const float* __restrict__ x,
    const int* __restrict__ row, const int* __restrict__ col,
    const __hip_bfloat16* __restrict__ radf,
    const float* __restrict__ pooled_x, const int* __restrict__ chsum,
    const float* __restrict__ e_w1, const float* __restrict__ e_b1,
    const float* __restrict__ e_w2, const float* __restrict__ e_b2,
    const float* __restrict__ att_w, const float* __restrict__ att_b,
    const float* __restrict__ c_w1, const float* __restrict__ c_b1,
    const float* __restrict__ c_w2, const float* __restrict__ c_b2,
    float* __restrict__ x_acc, float* __restrict__ agg, int Ee) {
  __shared__ float s_a[TE][128];   // h[row]
  __shared__ float s_b[TE][128];   // h[col]
  __shared__ float s_c[TE][128];   // radial feat
  __shared__ float s_d[TE][128];   // ef1 / cmh
  __shared__ float s_e[TE][128];   // ef2 / gated ef
  __shared__ float s_xr[TE][42];
  __shared__ float s_pc[TE][3];
  __shared__ float s_cm[TE][14];
  __shared__ float s_pool[TE][14];
  __shared__ float s_red[TE][16];
  __shared__ float s_att[TE];
  __shared__ int s_row[TE], s_col[TE], s_cs[TE];

  const int t = threadIdx.x;
  const int e0 = blockIdx.x * TE;
  const int ne = min(TE, Ee - e0);

  if (t < TE) {
    int e = e0 + min(t, ne - 1);
    s_row[t] = row[e];
    s_col[t] = col[e];
    s_cs[t] = chsum[s_row[t]];
  }
  __syncthreads();
  for (int i = t; i < TE * 128; i += 256) {
    int e = i >> 7, k = i & 127;
    s_a[e][k] = h[(size_t)s_row[e] * 128 + k];
    s_b[e][k] = h[(size_t)s_col[e] * 128 + k];
    int ge = e0 + min(e, ne - 1);
    s_c[e][k] = __bfloat162float(radf[(size_t)ge * 128 + k]);
  }
  for (int i = t; i < TE * 42; i += 256) {
    int e = i / 42, r = i % 42;
    s_xr[e][r] = x[(size_t)s_row[e] * 42 + r];
  }
  if (t < TE * 3) {
    int e = t / 3, d = t % 3;
    s_pc[e][d] = pooled_x[(size_t)s_col[e] * 3 + d];
  }
  __syncthreads();
  const int o4 = (t & 31) * 4, g = t >> 5;
  // ef1 = silu([h_row | h_col | radial] @ e_w1 + e_b1)
  {
    float acc[2][4] = {};
    gemm_acc(s_a, e_w1, o4, g, acc);
    gemm_acc(s_b, e_w1 + 128 * 128, o4, g, acc);
    gemm_acc(s_c, e_w1 + 256 * 128, o4, g, acc);
    float4 b = *(const float4*)&e_b1[o4];
#pragma unroll
    for (int ee = 0; ee < 2; ee++) {
      float4 v = make_float4(siluf(acc[ee][0] + b.x), siluf(acc[ee][1] + b.y),
                             siluf(acc[ee][2] + b.z), siluf(acc[ee][3] + b.w));
      *(float4*)&s_d[g * 2 + ee][o4] = v;
    }
  }
  __syncthreads();
  // ef2 = silu(ef1 @ e_w2 + e_b2)
  {
    float acc[2][4] = {};
    gemm_acc(s_d, e_w2, o4, g, acc);
    float4 b = *(const float4*)&e_b2[o4];
#pragma unroll
    for (int ee = 0; ee < 2; ee++) {
      float4 v = make_float4(siluf(acc[ee][0] + b.x), siluf(acc[ee][1] + b.y),
                             siluf(acc[ee][2] + b.z), siluf(acc[ee][3] + b.w));
      *(float4*)&s_e[g * 2 + ee][o4] = v;
    }
  }
  __syncthreads();
  // attention gate: ef *= sigmoid(ef2 @ att_w + att_b)
  {
    int e = t >> 4, p = t & 15;
    float s = 0.f;
#pragma unroll
    for (int j = 0; j < 8; j++) s += s_e[e][p * 8 + j] * att_w[p * 8 + j];
    s_red[e][p] = s;
  }
  __syncthreads();
  if (t < TE) {
    float s = 0.f;
#pragma unroll
    for (int i = 0; i < 16; i++) s += s_red[t][i];
    s_att[t] = sigmf(s + att_b[0]);
  }
  __syncthreads();
  for (int i = t; i < TE * 128; i += 256) {
    int e = i >> 7;
    s_e[e][i & 127] *= s_att[e];
  }
  __syncthreads();
  // cmh = silu(ef @ c_w1 + c_b1)
  {
    float acc[2][4] = {};
    gemm_acc(s_e, c_w1, o4, g, acc);
    float4 b = *(const float4*)&c_b1[o4];
#pragma unroll
    for (int ee = 0; ee < 2; ee++) {
      float4 v = make_float4(siluf(acc[ee][0] + b.x), siluf(acc[ee][1] + b.y),
                             siluf(acc[ee][2] + b.z), siluf(acc[ee][3] + b.w));
      *(float4*)&s_d[g * 2 + ee][o4] = v;
    }
  }
  __syncthreads();
  // cm = cmh @ c_w2 + c_b2
  if (t < TE * 14) {
    int e = t / 14, c = t % 14;
    float acc = c_b2[c];
    for (int k = 0; k < 128; k++) acc += s_d[e][k] * c_w2[k * 14 + c];
    s_cm[e][c] = acc;
  }
  __syncthreads();
  // RollerPooling: windowed mean, window ws = 15 - channel_sum[row]
  if (t < TE * 14) {
    int e = t / 14, c = t % 14;
    int wsz = 15 - s_cs[e];
    int hi = min(c + wsz, 14);
    float s = 0.f;
    for (int j = c; j < hi; j++) s += s_cm[e][j];
    s_pool[e][c] = s / (float)wsz;
  }
  __syncthreads();
  // trans scatter to x_acc[row]
  for (int i = t; i < TE * 42; i += 256) {
    int e = i / 42, r = i % 42, c = r / 3, d = r % 3;
    if (e < ne) {
      float v = (s_xr[e][r] - s_pc[e][d]) * s_pool[e][c];
      unsafeAtomicAdd(&x_acc[(size_t)s_row[e] * 42 + r], v);
    }
  }
  // ef scatter to agg[col]
  for (int i = t; i < TE * 128; i += 256) {
    int e = i >> 7, o = i & 127;
    if (e < ne) unsafeAtomicAdd(&agg[(size_t)s_col[e] * 128 + o], s_e[e][o]);
  }
}

// ---- node MLP + residual + LayerNorm ----
__global__ __launch_bounds__(256) void k_node(
    const float* __restrict__ h, const float* __restrict__ agg,
    const unsigned* __restrict__ cnt_col,
    const float* __restrict__ n_w1, const float* __restrict__ n_b1,
    const float* __restrict__ n_w2, const float* __restrict__ n_b2,
    const float* __restrict__ ln_g, const float* __restrict__ ln_b,
    float* __restrict__ out_h, int Nn) {
  __shared__ float s_h[TN][128], s_g[TN][128], s_d[TN][128], s_o[TN][128];
  __shared__ float s_red[TN][16], s_mu[TN], s_rs[TN];
  const int t = threadIdx.x;
  const int n0 = blockIdx.x * TN;
  const int nn = min(TN, Nn - n0);
  for (int i = t; i < TN * 128; i += 256) {
    int n = i >> 7, k = i & 127;
    int gn = n0 + min(n, nn - 1);
    s_h[n][k] = h[(size_t)gn * 128 + k];
    unsigned c = cnt_col[gn];
    s_g[n][k] = agg[(size_t)gn * 128 + k] / (float)(c > 0 ? c : 1);
  }
  __syncthreads();
  const int o4 = (t & 31) * 4, g = t >> 5;
  {
    float acc[2][4] = {};
    gemm_acc(s_h, n_w1, o4, g, acc);
    gemm_acc(s_g, n_w1 + 128 * 128, o4, g, acc);
    float4 b = *(const float4*)&n_b1[o4];
#pragma unroll
    for (int ee = 0; ee < 2; ee++) {
      float4 v = make_float4(siluf(acc[ee][0] + b.x), siluf(acc[ee][1] + b.y),
                             siluf(acc[ee][2] + b.z), siluf(acc[ee][3] + b.w));
      *(float4*)&s_d[g * 2 + ee][o4] = v;
    }
  }
  __syncthreads();
  {
    float acc[2][4] = {};
    gemm_acc(s_d, n_w2, o4, g, acc);
    float4 b = *(const float4*)&n_b2[o4];
#pragma unroll
    for (int ee = 0; ee < 2; ee++) {
      int n = g * 2 + ee;
      s_o[n][o4 + 0] = s_h[n][o4 + 0] + acc[ee][0] + b.x;
      s_o[n][o4 + 1] = s_h[n][o4 + 1] + acc[ee][1] + b.y;
      s_o[n][o4 + 2] = s_h[n][o4 + 2] + acc[ee][2] + b.z;
      s_o[n][o4 + 3] = s_h[n][o4 + 3] + acc[ee][3] + b.w;
    }
  }
  __syncthreads();
  {
    int n = t >> 4, p = t & 15;
    float s = 0.f;
#pragma unroll
    for (int j = 0; j < 8; j++) s += s_o[n][p * 8 + j];
    s_red[n][p] = s;
  }
  __syncthreads();
  if (t < TN) {
    float s = 0.f;
#pragma unroll
    for (int i = 0; i < 16; i++) s += s_red[t][i];
    s_mu[t] = s * (1.f / 128.f);
  }
  __syncthreads();
  {
    int n = t >> 4, p = t & 15;
    float mu = s_mu[n], s = 0.f;
#pragma unroll
    for (int j = 0; j < 8; j++) {
      float d = s_o[n][p * 8 + j] - mu;
      s += d * d;
    }
    s_red[n][p] = s;
  }
  __syncthreads();
  if (t < TN) {
    float s = 0.f;
#pragma unroll
    for (int i = 0; i < 16; i++) s += s_red[t][i];
    s_rs[t] = rsqrtf(s * (1.f / 128.f) + 1e-5f);
  }
  __syncthreads();
  for (int i = t; i < TN * 128; i += 256) {
    int n = i >> 7, k = i & 127;
    if (n < nn)
      out_h[(size_t)(n0 + n) * 128 + k] = (s_o[n][k] - s_mu[n]) * s_rs[n] * ln_g[k] + ln_b[k];
  }
}

// ---- x_new = x + x_acc / max(cnt_row, 1) ----
__global__ __launch_bounds__(256) void k_xnew(const float* __restrict__ x,
                                              const float* __restrict__ x_acc,
                                              const unsigned* __restrict__ cnt_row,
                                              float* __restrict__ out_x, int Nn) {
  int i = blockIdx.x * 256 + threadIdx.x;
  int total = Nn * 42;
  if (i >= total) return;
  int n = i / 42;
  unsigned c = cnt_row[n];
  out_x[i] = x[i] + x_acc[i] / (float)(c > 0 ? c : 1);
}

extern "C" void kernel_launch(void* const* d_in, const int* in_sizes, int n_in,
                              void* d_out, int out_size, void* d_ws, size_t ws_size,
                              hipStream_t stream) {
  const float* h     = (const float*)d_in[0];
  const float* x     = (const float*)d_in[1];
  const float* attr  = (const float*)d_in[2];
  const float* cw    = (const float*)d_in[3];
  const int*   row   = (const int*)d_in[4];
  const int*   col   = (const int*)d_in[5];
  const float* rad_w = (const float*)d_in[6];
  const float* rad_b = (const float*)d_in[7];
  const float* e_w1  = (const float*)d_in[8];
  const float* e_b1  = (const float*)d_in[9];
  const float* e_w2  = (const float*)d_in[10];
  const float* e_b2  = (const float*)d_in[11];
  const float* att_w = (const float*)d_in[12];
  const float* att_b = (const float*)d_in[13];
  const float* c_w1  = (const float*)d_in[14];
  const float* c_b1  = (const float*)d_in[15];
  const float* c_w2  = (const float*)d_in[16];
  const float* c_b2  = (const float*)d_in[17];
  const float* n_w1  = (const float*)d_in[18];
  const float* n_b1  = (const float*)d_in[19];
  const float* n_w2  = (const float*)d_in[20];
  const float* n_b2  = (const float*)d_in[21];
  const float* ln_g  = (const float*)d_in[22];
  const float* ln_b  = (const float*)d_in[23];

  const int N = in_sizes[0] / 128;
  const int E = in_sizes[4];

  char* ws = (char*)d_ws;
  size_t off = 0;
  auto alloc = [&](size_t bytes) {
    size_t o = off;
    off += (bytes + 255) & ~(size_t)255;
    return o;
  };
  size_t off_radf = alloc((size_t)E * 128 * sizeof(__hip_bfloat16));
  size_t off_px   = alloc((size_t)N * 3 * sizeof(float));
  size_t off_cs   = alloc((size_t)N * sizeof(int));
  size_t off_cntr = alloc((size_t)N * sizeof(unsigned));
  size_t off_cntc = alloc((size_t)N * sizeof(unsigned));
  size_t off_xacc = alloc((size_t)N * 42 * sizeof(float));
  size_t off_agg  = alloc((size_t)N * 128 * sizeof(float));

  __hip_bfloat16* radf = (__hip_bfloat16*)(ws + off_radf);
  float* pooled_x = (float*)(ws + off_px);
  int* chsum      = (int*)(ws + off_cs);
  unsigned* cnt_row = (unsigned*)(ws + off_cntr);
  unsigned* cnt_col = (unsigned*)(ws + off_cntc);
  float* x_acc    = (float*)(ws + off_xacc);
  float* agg      = (float*)(ws + off_agg);

  // zero the atomic accumulators (cnt_row .. agg are contiguous)
  hipMemsetAsync(ws + off_cntr, 0, off - off_cntr, stream);

  k_prep<<<dim3((N + 255) / 256), dim3(256), 0, stream>>>(x, cw, pooled_x, chsum, N);
  k_radial<<<dim3((E + TE - 1) / TE), dim3(256), 0, stream>>>(
      x, attr, cw, row, col, rad_w, rad_b, radf, cnt_row, cnt_col, E);
  k_edge<<<dim3((E + TE - 1) / TE), dim3(256), 0, stream>>>(
      h, x, row, col, radf, pooled_x, chsum,
      e_w1, e_b1, e_w2, e_b2, att_w, att_b, c_w1, c_b1, c_w2, c_b2,
      x_acc, agg, E);
  k_node<<<dim3((N + TN - 1) / TN), dim3(256), 0, stream>>>(
      h, agg, cnt_col, n_w1, n_b1, n_w2, n_b2, ln_g, ln_b, (float*)d_out, N);
  k_xnew<<<dim3((N * 42 + 255) / 256), dim3(256), 0, stream>>>(
      x, x_acc, cnt_row, (float*)d_out + (size_t)N * 128, N);
}

// Round 2
// 813.705 us; speedup vs baseline: 2.1531x; 2.1531x over previous
//
#include <hip/hip_runtime.h>
#include <hip/hip_bf16.h>

// EnhancedGNNEncoder round 2: bf16 MFMA for edge/radial GEMM chains.
//   memset -> k_wswz (weight bf16 swizzle) -> k_prep -> k_radial -> k_edge
//          -> k_node -> k_xnew
// Weights pre-swizzled to B-fragment layout [K/32][128][32] bf16 so B frags
// load coalesced straight from global (L1/L2-hot). A-tiles staged in LDS in
// fragment-blocked [kb][16][32] bf16 layout. MFMA 16x16x32:
//   A[m=lane&15][k=quad*8+j], B[k=quad*8+j][n=lane&15], D col=lane&15 row=quad*4+r.

#define TE 16
#define TN 16

typedef __attribute__((ext_vector_type(8))) short bf16x8;
typedef __attribute__((ext_vector_type(4))) float f32x4;

__device__ __forceinline__ float siluf(float v) { return v / (1.f + __expf(-v)); }
__device__ __forceinline__ float sigmf(float v) { return 1.f / (1.f + __expf(-v)); }

// fp32 register-tile GEMM (kept for k_node)
__device__ __forceinline__ void gemm_acc(const float (*__restrict__ src)[128],
                                         const float* __restrict__ W,
                                         int o4, int g, float acc[2][4]) {
  for (int k = 0; k < 128; k += 4) {
    float4 w0 = *(const float4*)&W[(k + 0) * 128 + o4];
    float4 w1 = *(const float4*)&W[(k + 1) * 128 + o4];
    float4 w2 = *(const float4*)&W[(k + 2) * 128 + o4];
    float4 w3 = *(const float4*)&W[(k + 3) * 128 + o4];
#pragma unroll
    for (int ee = 0; ee < 2; ee++) {
      const float4 r = *(const float4*)&src[g * 2 + ee][k];
      acc[ee][0] = fmaf(r.x, w0.x, fmaf(r.y, w1.x, fmaf(r.z, w2.x, fmaf(r.w, w3.x, acc[ee][0]))));
      acc[ee][1] = fmaf(r.x, w0.y, fmaf(r.y, w1.y, fmaf(r.z, w2.y, fmaf(r.w, w3.y, acc[ee][1]))));
      acc[ee][2] = fmaf(r.x, w0.z, fmaf(r.y, w1.z, fmaf(r.z, w2.z, fmaf(r.w, w3.z, acc[ee][2]))));
      acc[ee][3] = fmaf(r.x, w0.w, fmaf(r.y, w1.w, fmaf(r.z, w2.w, fmaf(r.w, w3.w, acc[ee][3]))));
    }
  }
}

// ---- weight swizzle: fp32 [K][128] -> bf16 [K/32][128][32] ----
__global__ __launch_bounds__(256) void k_wswz(
    const float* __restrict__ rad_w, const float* __restrict__ e_w1,
    const float* __restrict__ e_w2, const float* __restrict__ c_w1,
    __hip_bfloat16* __restrict__ wz_rad, __hip_bfloat16* __restrict__ wz_e1,
    __hip_bfloat16* __restrict__ wz_e2, __hip_bfloat16* __restrict__ wz_c1) {
  int i = blockIdx.x * 256 + threadIdx.x;
  const float* W;
  __hip_bfloat16* O;
  int base;
  if (i < 32768) { W = rad_w; O = wz_rad; base = i; }
  else if (i < 81920) { W = e_w1; O = wz_e1; base = i - 32768; }
  else if (i < 98304) { W = e_w2; O = wz_e2; base = i - 81920; }
  else if (i < 114688) { W = c_w1; O = wz_c1; base = i - 98304; }
  else return;
  int k = base >> 7, n = base & 127;
  O[(size_t)((k >> 5) * 128 + n) * 32 + (k & 31)] = __float2bfloat16(W[base]);
}

// ---- per-node prep ----
__global__ __launch_bounds__(256) void k_prep(const float* __restrict__ x,
                                              const float* __restrict__ cw,
                                              float* __restrict__ pooled_x,
                                              int* __restrict__ chsum, int Nn) {
  int n = blockIdx.x * 256 + threadIdx.x;
  if (n >= Nn) return;
  int cnt = 0;
  float sx = 0.f, sy = 0.f, sz = 0.f;
#pragma unroll
  for (int c = 0; c < 14; c++) {
    float w = cw[n * 14 + c];
    if (w != 0.f) {
      cnt++;
      sx += x[n * 42 + c * 3 + 0];
      sy += x[n * 42 + c * 3 + 1];
      sz += x[n * 42 + c * 3 + 2];
    }
  }
  chsum[n] = cnt;
  float inv = 1.f / (float)(cnt > 0 ? cnt : 1);
  pooled_x[n * 3 + 0] = sx * inv;
  pooled_x[n * 3 + 1] = sy * inv;
  pooled_x[n * 3 + 2] = sz * inv;
}

// ---- radial: einsum (VALU) + rad_w GEMM (MFMA) ----
__global__ __launch_bounds__(256) void k_radial(
    const float* __restrict__ x, const float* __restrict__ attr, const float* __restrict__ cw,
    const int* __restrict__ row, const int* __restrict__ col,
    const __hip_bfloat16* __restrict__ wz_rad, const float* __restrict__ rad_b,
    __hip_bfloat16* __restrict__ radf,
    unsigned* __restrict__ cnt_row, unsigned* __restrict__ cnt_col, int Ee) {
  __shared__ float s_xr[TE][14][3], s_xc[TE][14][3];
  __shared__ float s_cwr[TE][14], s_cwc[TE][14];
  __shared__ __hip_bfloat16 s_ar[TE][14][16], s_ac[TE][14][16];
  __shared__ __hip_bfloat16 s_msg[TE][14][14];
  __shared__ __hip_bfloat16 s_m1[TE][14][16];
  __shared__ __hip_bfloat16 s_radA[8][16][32];  // radial, fragment-blocked bf16
  __shared__ float s_red[TE][16];
  __shared__ float s_rn[TE];
  __shared__ int s_row[TE], s_col[TE];

  const int t = threadIdx.x;
  const int e0 = blockIdx.x * TE;
  const int ne = min(TE, Ee - e0);

  if (t < TE) {
    int e = e0 + min(t, ne - 1);
    s_row[t] = row[e];
    s_col[t] = col[e];
    if (t < ne) {
      atomicAdd(&cnt_row[s_row[t]], 1u);
      atomicAdd(&cnt_col[s_col[t]], 1u);
    }
  }
  __syncthreads();
  for (int i = t; i < TE * 42; i += 256) {
    int e = i / 42, r = i % 42;
    s_xr[e][r / 3][r % 3] = x[(size_t)s_row[e] * 42 + r];
    s_xc[e][r / 3][r % 3] = x[(size_t)s_col[e] * 42 + r];
  }
  for (int i = t; i < TE * 14; i += 256) {
    int e = i / 14, c = i % 14;
    s_cwr[e][c] = cw[(size_t)s_row[e] * 14 + c];
    s_cwc[e][c] = cw[(size_t)s_col[e] * 14 + c];
  }
  for (int i = t; i < TE * 224; i += 256) {
    int e = i / 224, r = i % 224;
    s_ar[e][r / 16][r % 16] = __float2bfloat16(attr[(size_t)s_row[e] * 224 + r]);
    s_ac[e][r / 16][r % 16] = __float2bfloat16(attr[(size_t)s_col[e] * 224 + r]);
  }
  __syncthreads();
  for (int i = t; i < TE * 196; i += 256) {
    int e = i / 196, r = i % 196, ci = r / 14, cj = r % 14;
    float dx = s_xr[e][ci][0] - s_xc[e][cj][0];
    float dy = s_xr[e][ci][1] - s_xc[e][cj][1];
    float dz = s_xr[e][ci][2] - s_xc[e][cj][2];
    float d = sqrtf(dx * dx + dy * dy + dz * dz);
    s_msg[e][ci][cj] = __float2bfloat16(d * s_cwr[e][ci] * s_cwc[e][cj]);
  }
  __syncthreads();
  for (int i = t; i < TE * 224; i += 256) {
    int e = i / 224, r = i % 224, c = r / 16, b = r % 16;
    float acc = 0.f;
#pragma unroll
    for (int j = 0; j < 14; j++)
      acc += __bfloat162float(s_msg[e][c][j]) * __bfloat162float(s_ac[e][j][b]);
    s_m1[e][c][b] = __float2bfloat16(acc);
  }
  __syncthreads();
  // radial[a*16+b]; store bf16 fragment-blocked; sumsq in fp32
  {
    int e = t >> 4, b = t & 15;
    float ss = 0.f;
#pragma unroll
    for (int a = 0; a < 16; a++) {
      float acc = 0.f;
#pragma unroll
      for (int c = 0; c < 14; c++)
        acc += __bfloat162float(s_ar[e][c][a]) * __bfloat162float(s_m1[e][c][b]);
      int k = a * 16 + b;
      s_radA[k >> 5][e][k & 31] = __float2bfloat16(acc);
      ss += acc * acc;
    }
    s_red[e][b] = ss;
  }
  __syncthreads();
  if (t < TE) {
    float s = 0.f;
#pragma unroll
    for (int i = 0; i < 16; i++) s += s_red[t][i];
    s_rn[t] = sqrtf(s) + 1.0f;
  }
  __syncthreads();
  // MFMA: radf = (radial @ rad_w + rad_b) / rn   (K=256 -> 8 kb)
  {
    const int lane = t & 63, wave = t >> 6, quad = lane >> 4, mr = lane & 15;
    const int n0 = wave * 32;
    f32x4 acc0 = {0.f, 0.f, 0.f, 0.f}, acc1 = {0.f, 0.f, 0.f, 0.f};
#pragma unroll
    for (int kb = 0; kb < 8; kb++) {
      bf16x8 a = *(const bf16x8*)&s_radA[kb][mr][quad * 8];
      const __hip_bfloat16* wp = wz_rad + ((size_t)(kb * 128 + n0 + mr) * 32 + quad * 8);
      bf16x8 b0 = *(const bf16x8*)wp;
      bf16x8 b1 = *(const bf16x8*)(wp + 16 * 32);
      acc0 = __builtin_amdgcn_mfma_f32_16x16x32_bf16(a, b0, acc0, 0, 0, 0);
      acc1 = __builtin_amdgcn_mfma_f32_16x16x32_bf16(a, b1, acc1, 0, 0, 0);
    }
    float bias0 = rad_b[n0 + mr], bias1 = rad_b[n0 + 16 + mr];
#pragma unroll
    for (int r = 0; r < 4; r++) {
      int e = quad * 4 + r;
      if (e < ne) {
        float inv = 1.f / s_rn[e];
        size_t base = (size_t)(e0 + e) * 128;
        radf[base + n0 + mr]      = __float2bfloat16((acc0[r] + bias0) * inv);
        radf[base + n0 + 16 + mr] = __float2bfloat16((acc1[r] + bias1) * inv);
      }
    }
  }
}

// ---- fused edge MLP chain (MFMA) + gate + RollerPooling + scatters ----
__global__ __launch_bounds__(256) void k_edge(
    const float* __restrict__ h, const float* __restrict__ x,
    const int* __restrict__ row, const int* __restrict__ col,
    const __hip_bfloat16* __restrict__ radf,
    const float* __restrict__ pooled_x, const int* __restrict__ chsum,
    const __hip_bfloat16* __restrict__ wz_e1, const float* __restrict__ e_b1,
    const __hip_bfloat16* __restrict__ wz_e2, const float* __restrict__ e_b2,
    const float* __restrict__ att_w, const float* __restrict__ att_b,
    const __hip_bfloat16* __restrict__ wz_c1, const float* __restrict__ c_b1,
    const float* __restrict__ c_w2, const float* __restrict__ c_b2,
    float* __restrict__ x_acc, float* __restrict__ agg, int Ee) {
  __shared__ __hip_bfloat16 sA[12][16][32];   // [h_row | h_col | radf], K=384
  __shared__ __hip_bfloat16 sT[4][16][32];    // ef1
  __shared__ __hip_bfloat16 sU[4][16][32];    // ef2 (ungated)
  __shared__ float sCmh[16][132];             // cmh fp32
  __shared__ float s_xr[TE][42];
  __shared__ float s_pc[TE][3];
  __shared__ float s_cm[TE][14];
  __shared__ float s_pool[TE][14];
  __shared__ float s_red[TE][16];
  __shared__ float s_att[TE];
  __shared__ int s_row[TE], s_col[TE], s_cs[TE];

  const int t = threadIdx.x;
  const int e0 = blockIdx.x * TE;
  const int ne = min(TE, Ee - e0);

  if (t < TE) {
    int e = e0 + min(t, ne - 1);
    s_row[t] = row[e];
    s_col[t] = col[e];
    s_cs[t] = chsum[s_row[t]];
  }
  __syncthreads();
  // stage A-tile: kb 0-3 h[row], 4-7 h[col], 8-11 radf
  for (int i = t; i < TE * 64; i += 256) {
    int m = i >> 6, kp = (i & 63) << 1;
    int kb = kp >> 5, kk = kp & 31;
    const float2 hv = *(const float2*)&h[(size_t)s_row[m] * 128 + kp];
    sA[kb][m][kk]     = __float2bfloat16(hv.x);
    sA[kb][m][kk + 1] = __float2bfloat16(hv.y);
    const float2 cv = *(const float2*)&h[(size_t)s_col[m] * 128 + kp];
    sA[4 + kb][m][kk]     = __float2bfloat16(cv.x);
    sA[4 + kb][m][kk + 1] = __float2bfloat16(cv.y);
    int ge = e0 + min(m, ne - 1);
    const __hip_bfloat16* rp = &radf[(size_t)ge * 128 + kp];
    sA[8 + kb][m][kk]     = rp[0];
    sA[8 + kb][m][kk + 1] = rp[1];
  }
  for (int i = t; i < TE * 42; i += 256) {
    int e = i / 42, r = i % 42;
    s_xr[e][r] = x[(size_t)s_row[e] * 42 + r];
  }
  if (t < TE * 3) {
    int e = t / 3, d = t % 3;
    s_pc[e][d] = pooled_x[(size_t)s_col[e] * 3 + d];
  }
  __syncthreads();

  const int lane = t & 63, wave = t >> 6, quad = lane >> 4, mr = lane & 15;
  const int n0 = wave * 32;

  // stage 1: ef1 = silu(A @ e_w1 + e_b1), K=384
  {
    f32x4 acc0 = {0.f, 0.f, 0.f, 0.f}, acc1 = {0.f, 0.f, 0.f, 0.f};
#pragma unroll
    for (int kb = 0; kb < 12; kb++) {
      bf16x8 a = *(const bf16x8*)&sA[kb][mr][quad * 8];
      const __hip_bfloat16* wp = wz_e1 + ((size_t)(kb * 128 + n0 + mr) * 32 + quad * 8);
      bf16x8 b0 = *(const bf16x8*)wp;
      bf16x8 b1 = *(const bf16x8*)(wp + 16 * 32);
      acc0 = __builtin_amdgcn_mfma_f32_16x16x32_bf16(a, b0, acc0, 0, 0, 0);
      acc1 = __builtin_amdgcn_mfma_f32_16x16x32_bf16(a, b1, acc1, 0, 0, 0);
    }
    float bias0 = e_b1[n0 + mr], bias1 = e_b1[n0 + 16 + mr];
#pragma unroll
    for (int r = 0; r < 4; r++) {
      int e = quad * 4 + r;
      sT[wave][e][mr]      = __float2bfloat16(siluf(acc0[r] + bias0));
      sT[wave][e][16 + mr] = __float2bfloat16(siluf(acc1[r] + bias1));
    }
  }
  __syncthreads();
  // stage 2: ef2 = silu(ef1 @ e_w2 + e_b2), K=128
  {
    f32x4 acc0 = {0.f, 0.f, 0.f, 0.f}, acc1 = {0.f, 0.f, 0.f, 0.f};
#pragma unroll
    for (int kb = 0; kb < 4; kb++) {
      bf16x8 a = *(const bf16x8*)&sT[kb][mr][quad * 8];
      const __hip_bfloat16* wp = wz_e2 + ((size_t)(kb * 128 + n0 + mr) * 32 + quad * 8);
      bf16x8 b0 = *(const bf16x8*)wp;
      bf16x8 b1 = *(const bf16x8*)(wp + 16 * 32);
      acc0 = __builtin_amdgcn_mfma_f32_16x16x32_bf16(a, b0, acc0, 0, 0, 0);
      acc1 = __builtin_amdgcn_mfma_f32_16x16x32_bf16(a, b1, acc1, 0, 0, 0);
    }
    float bias0 = e_b2[n0 + mr], bias1 = e_b2[n0 + 16 + mr];
#pragma unroll
    for (int r = 0; r < 4; r++) {
      int e = quad * 4 + r;
      sU[wave][e][mr]      = __float2bfloat16(siluf(acc0[r] + bias0));
      sU[wave][e][16 + mr] = __float2bfloat16(siluf(acc1[r] + bias1));
    }
  }
  __syncthreads();
  // attention gate scalar per edge
  {
    int e = t >> 4, p = t & 15;
    float s = 0.f;
#pragma unroll
    for (int j = 0; j < 8; j++) {
      int k = p * 8 + j;
      s += __bfloat162float(sU[k >> 5][e][k & 31]) * att_w[k];
    }
    s_red[e][p] = s;
  }
  __syncthreads();
  if (t < TE) {
    float s = 0.f;
#pragma unroll
    for (int i = 0; i < 16; i++) s += s_red[t][i];
    s_att[t] = sigmf(s + att_b[0]);
  }
  __syncthreads();
  // stage 3: cmh = silu(att*(ef2 @ c_w1) + c_b1)   [gating folded into acc scale]
  {
    f32x4 acc0 = {0.f, 0.f, 0.f, 0.f}, acc1 = {0.f, 0.f, 0.f, 0.f};
#pragma unroll
    for (int kb = 0; kb < 4; kb++) {
      bf16x8 a = *(const bf16x8*)&sU[kb][mr][quad * 8];
      const __hip_bfloat16* wp = wz_c1 + ((size_t)(kb * 128 + n0 + mr) * 32 + quad * 8);
      bf16x8 b0 = *(const bf16x8*)wp;
      bf16x8 b1 = *(const bf16x8*)(wp + 16 * 32);
      acc0 = __builtin_amdgcn_mfma_f32_16x16x32_bf16(a, b0, acc0, 0, 0, 0);
      acc1 = __builtin_amdgcn_mfma_f32_16x16x32_bf16(a, b1, acc1, 0, 0, 0);
    }
    float bias0 = c_b1[n0 + mr], bias1 = c_b1[n0 + 16 + mr];
#pragma unroll
    for (int r = 0; r < 4; r++) {
      int e = quad * 4 + r;
      float av = s_att[e];
      sCmh[e][n0 + mr]      = siluf(av * acc0[r] + bias0);
      sCmh[e][n0 + 16 + mr] = siluf(av * acc1[r] + bias1);
    }
  }
  __syncthreads();
  // cm = cmh @ c_w2 + c_b2
  if (t < TE * 14) {
    int e = t / 14, c = t % 14;
    float acc = c_b2[c];
    for (int k = 0; k < 128; k++) acc += sCmh[e][k] * c_w2[k * 14 + c];
    s_cm[e][c] = acc;
  }
  __syncthreads();
  // RollerPooling
  if (t < TE * 14) {
    int e = t / 14, c = t % 14;
    int wsz = 15 - s_cs[e];
    int hi = min(c + wsz, 14);
    float s = 0.f;
    for (int j = c; j < hi; j++) s += s_cm[e][j];
    s_pool[e][c] = s / (float)wsz;
  }
  __syncthreads();
  // trans scatter
  for (int i = t; i < TE * 42; i += 256) {
    int e = i / 42, r = i % 42, c = r / 3, d = r % 3;
    if (e < ne) {
      float v = (s_xr[e][r] - s_pc[e][d]) * s_pool[e][c];
      unsafeAtomicAdd(&x_acc[(size_t)s_row[e] * 42 + r], v);
    }
  }
  // agg scatter (gated ef2)
  for (int i = t; i < TE * 128; i += 256) {
    int e = i >> 7, o = i & 127;
    if (e < ne) {
      float v = __bfloat162float(sU[o >> 5][e][o & 31]) * s_att[e];
      unsafeAtomicAdd(&agg[(size_t)s_col[e] * 128 + o], v);
    }
  }
}

// ---- node MLP + residual + LayerNorm (fp32) ----
__global__ __launch_bounds__(256) void k_node(
    const float* __restrict__ h, const float* __restrict__ agg,
    const unsigned* __restrict__ cnt_col,
    const float* __restrict__ n_w1, const float* __restrict__ n_b1,
    const float* __restrict__ n_w2, const float* __restrict__ n_b2,
    const float* __restrict__ ln_g, const float* __restrict__ ln_b,
    float* __restrict__ out_h, int Nn) {
  __shared__ float s_h[TN][128], s_g[TN][128], s_d[TN][128], s_o[TN][128];
  __shared__ float s_red[TN][16], s_mu[TN], s_rs[TN];
  const int t = threadIdx.x;
  const int n0 = blockIdx.x * TN;
  const int nn = min(TN, Nn - n0);
  for (int i = t; i < TN * 128; i += 256) {
    int n = i >> 7, k = i & 127;
    int gn = n0 + min(n, nn - 1);
    s_h[n][k] = h[(size_t)gn * 128 + k];
    unsigned c = cnt_col[gn];
    s_g[n][k] = agg[(size_t)gn * 128 + k] / (float)(c > 0 ? c : 1);
  }
  __syncthreads();
  const int o4 = (t & 31) * 4, g = t >> 5;
  {
    float acc[2][4] = {};
    gemm_acc(s_h, n_w1, o4, g, acc);
    gemm_acc(s_g, n_w1 + 128 * 128, o4, g, acc);
    float4 b = *(const float4*)&n_b1[o4];
#pragma unroll
    for (int ee = 0; ee < 2; ee++) {
      float4 v = make_float4(siluf(acc[ee][0] + b.x), siluf(acc[ee][1] + b.y),
                             siluf(acc[ee][2] + b.z), siluf(acc[ee][3] + b.w));
      *(float4*)&s_d[g * 2 + ee][o4] = v;
    }
  }
  __syncthreads();
  {
    float acc[2][4] = {};
    gemm_acc(s_d, n_w2, o4, g, acc);
    float4 b = *(const float4*)&n_b2[o4];
#pragma unroll
    for (int ee = 0; ee < 2; ee++) {
      int n = g * 2 + ee;
      s_o[n][o4 + 0] = s_h[n][o4 + 0] + acc[ee][0] + b.x;
      s_o[n][o4 + 1] = s_h[n][o4 + 1] + acc[ee][1] + b.y;
      s_o[n][o4 + 2] = s_h[n][o4 + 2] + acc[ee][2] + b.z;
      s_o[n][o4 + 3] = s_h[n][o4 + 3] + acc[ee][3] + b.w;
    }
  }
  __syncthreads();
  {
    int n = t >> 4, p = t & 15;
    float s = 0.f;
#pragma unroll
    for (int j = 0; j < 8; j++) s += s_o[n][p * 8 + j];
    s_red[n][p] = s;
  }
  __syncthreads();
  if (t < TN) {
    float s = 0.f;
#pragma unroll
    for (int i = 0; i < 16; i++) s += s_red[t][i];
    s_mu[t] = s * (1.f / 128.f);
  }
  __syncthreads();
  {
    int n = t >> 4, p = t & 15;
    float mu = s_mu[n], s = 0.f;
#pragma unroll
    for (int j = 0; j < 8; j++) {
      float d = s_o[n][p * 8 + j] - mu;
      s += d * d;
    }
    s_red[n][p] = s;
  }
  __syncthreads();
  if (t < TN) {
    float s = 0.f;
#pragma unroll
    for (int i = 0; i < 16; i++) s += s_red[t][i];
    s_rs[t] = rsqrtf(s * (1.f / 128.f) + 1e-5f);
  }
  __syncthreads();
  for (int i = t; i < TN * 128; i += 256) {
    int n = i >> 7, k = i & 127;
    if (n < nn)
      out_h[(size_t)(n0 + n) * 128 + k] = (s_o[n][k] - s_mu[n]) * s_rs[n] * ln_g[k] + ln_b[k];
  }
}

__global__ __launch_bounds__(256) void k_xnew(const float* __restrict__ x,
                                              const float* __restrict__ x_acc,
                                              const unsigned* __restrict__ cnt_row,
                                              float* __restrict__ out_x, int Nn) {
  int i = blockIdx.x * 256 + threadIdx.x;
  int total = Nn * 42;
  if (i >= total) return;
  int n = i / 42;
  unsigned c = cnt_row[n];
  out_x[i] = x[i] + x_acc[i] / (float)(c > 0 ? c : 1);
}

extern "C" void kernel_launch(void* const* d_in, const int* in_sizes, int n_in,
                              void* d_out, int out_size, void* d_ws, size_t ws_size,
                              hipStream_t stream) {
  const float* h     = (const float*)d_in[0];
  const float* x     = (const float*)d_in[1];
  const float* attr  = (const float*)d_in[2];
  const float* cw    = (const float*)d_in[3];
  const int*   row   = (const int*)d_in[4];
  const int*   col   = (const int*)d_in[5];
  const float* rad_w = (const float*)d_in[6];
  const float* rad_b = (const float*)d_in[7];
  const float* e_w1  = (const float*)d_in[8];
  const float* e_b1  = (const float*)d_in[9];
  const float* e_w2  = (const float*)d_in[10];
  const float* e_b2  = (const float*)d_in[11];
  const float* att_w = (const float*)d_in[12];
  const float* att_b = (const float*)d_in[13];
  const float* c_w1  = (const float*)d_in[14];
  const float* c_b1  = (const float*)d_in[15];
  const float* c_w2  = (const float*)d_in[16];
  const float* c_b2  = (const float*)d_in[17];
  const float* n_w1  = (const float*)d_in[18];
  const float* n_b1  = (const float*)d_in[19];
  const float* n_w2  = (const float*)d_in[20];
  const float* n_b2  = (const float*)d_in[21];
  const float* ln_g  = (const float*)d_in[22];
  const float* ln_b  = (const float*)d_in[23];

  const int N = in_sizes[0] / 128;
  const int E = in_sizes[4];

  char* ws = (char*)d_ws;
  size_t off = 0;
  auto alloc = [&](size_t bytes) {
    size_t o = off;
    off += (bytes + 255) & ~(size_t)255;
    return o;
  };
  size_t off_radf = alloc((size_t)E * 128 * sizeof(__hip_bfloat16));
  size_t off_wzr  = alloc(32768 * sizeof(__hip_bfloat16));
  size_t off_wz1  = alloc(49152 * sizeof(__hip_bfloat16));
  size_t off_wz2  = alloc(16384 * sizeof(__hip_bfloat16));
  size_t off_wzc  = alloc(16384 * sizeof(__hip_bfloat16));
  size_t off_px   = alloc((size_t)N * 3 * sizeof(float));
  size_t off_cs   = alloc((size_t)N * sizeof(int));
  size_t off_cntr = alloc((size_t)N * sizeof(unsigned));
  size_t off_cntc = alloc((size_t)N * sizeof(unsigned));
  size_t off_xacc = alloc((size_t)N * 42 * sizeof(float));
  size_t off_agg  = alloc((size_t)N * 128 * sizeof(float));

  __hip_bfloat16* radf   = (__hip_bfloat16*)(ws + off_radf);
  __hip_bfloat16* wz_rad = (__hip_bfloat16*)(ws + off_wzr);
  __hip_bfloat16* wz_e1  = (__hip_bfloat16*)(ws + off_wz1);
  __hip_bfloat16* wz_e2  = (__hip_bfloat16*)(ws + off_wz2);
  __hip_bfloat16* wz_c1  = (__hip_bfloat16*)(ws + off_wzc);
  float* pooled_x  = (float*)(ws + off_px);
  int* chsum       = (int*)(ws + off_cs);
  unsigned* cnt_row = (unsigned*)(ws + off_cntr);
  unsigned* cnt_col = (unsigned*)(ws + off_cntc);
  float* x_acc     = (float*)(ws + off_xacc);
  float* agg       = (float*)(ws + off_agg);

  hipMemsetAsync(ws + off_cntr, 0, off - off_cntr, stream);

  k_wswz<<<dim3((114688 + 255) / 256), dim3(256), 0, stream>>>(
      rad_w, e_w1, e_w2, c_w1, wz_rad, wz_e1, wz_e2, wz_c1);
  k_prep<<<dim3((N + 255) / 256), dim3(256), 0, stream>>>(x, cw, pooled_x, chsum, N);
  k_radial<<<dim3((E + TE - 1) / TE), dim3(256), 0, stream>>>(
      x, attr, cw, row, col, wz_rad, rad_b, radf, cnt_row, cnt_col, E);
  k_edge<<<dim3((E + TE - 1) / TE), dim3(256), 0, stream>>>(
      h, x, row, col, radf, pooled_x, chsum,
      wz_e1, e_b1, wz_e2, e_b2, att_w, att_b, wz_c1, c_b1, c_w2, c_b2,
      x_acc, agg, E);
  k_node<<<dim3((N + TN - 1) / TN), dim3(256), 0, stream>>>(
      h, agg, cnt_col, n_w1, n_b1, n_w2, n_b2, ln_g, ln_b, (float*)d_out, N);
  k_xnew<<<dim3((N * 42 + 255) / 256), dim3(256), 0, stream>>>(
      x, x_acc, cnt_row, (float*)d_out + (size_t)N * 128, N);
}

// Round 3
// 785.284 us; speedup vs baseline: 2.2310x; 1.0362x over previous
//
#include <hip/hip_runtime.h>
#include <hip/hip_bf16.h>

// EnhancedGNNEncoder round 3:
//  - k_radial einsum now MFMA: per-edge M1 = D @ Ac', radial = Ar'^T @ M1
//    (cw folded into attr operands; K padded 14->32 with zeros).
//  - k_node ported to bf16 MFMA with pre-swizzled n_w1/n_w2.
// MFMA 16x16x32 layouts: A[m=lane&15][k=quad*8+j], B-frag from Bt[n][k]
// (lane n=lane&15, k=quad*8+j), D col=lane&15 row=quad*4+reg.

#define TE 16
#define TN 16

typedef __attribute__((ext_vector_type(8))) short bf16x8;
typedef __attribute__((ext_vector_type(4))) float f32x4;

__device__ __forceinline__ float siluf(float v) { return v / (1.f + __expf(-v)); }
__device__ __forceinline__ float sigmf(float v) { return 1.f / (1.f + __expf(-v)); }

// ---- weight swizzle: fp32 [K][128] -> bf16 [K/32][128][32] ----
__global__ __launch_bounds__(256) void k_wswz(
    const float* __restrict__ rad_w, const float* __restrict__ e_w1,
    const float* __restrict__ e_w2, const float* __restrict__ c_w1,
    const float* __restrict__ n_w1, const float* __restrict__ n_w2,
    __hip_bfloat16* __restrict__ wz_rad, __hip_bfloat16* __restrict__ wz_e1,
    __hip_bfloat16* __restrict__ wz_e2, __hip_bfloat16* __restrict__ wz_c1,
    __hip_bfloat16* __restrict__ wz_n1, __hip_bfloat16* __restrict__ wz_n2) {
  int i = blockIdx.x * 256 + threadIdx.x;
  const float* W;
  __hip_bfloat16* O;
  int base;
  if (i < 32768) { W = rad_w; O = wz_rad; base = i; }
  else if (i < 81920) { W = e_w1; O = wz_e1; base = i - 32768; }
  else if (i < 98304) { W = e_w2; O = wz_e2; base = i - 81920; }
  else if (i < 114688) { W = c_w1; O = wz_c1; base = i - 98304; }
  else if (i < 147456) { W = n_w1; O = wz_n1; base = i - 114688; }
  else if (i < 163840) { W = n_w2; O = wz_n2; base = i - 147456; }
  else return;
  int k = base >> 7, n = base & 127;
  O[(size_t)((k >> 5) * 128 + n) * 32 + (k & 31)] = __float2bfloat16(W[base]);
}

// ---- per-node prep ----
__global__ __launch_bounds__(256) void k_prep(const float* __restrict__ x,
                                              const float* __restrict__ cw,
                                              float* __restrict__ pooled_x,
                                              int* __restrict__ chsum, int Nn) {
  int n = blockIdx.x * 256 + threadIdx.x;
  if (n >= Nn) return;
  int cnt = 0;
  float sx = 0.f, sy = 0.f, sz = 0.f;
#pragma unroll
  for (int c = 0; c < 14; c++) {
    float w = cw[n * 14 + c];
    if (w != 0.f) {
      cnt++;
      sx += x[n * 42 + c * 3 + 0];
      sy += x[n * 42 + c * 3 + 1];
      sz += x[n * 42 + c * 3 + 2];
    }
  }
  chsum[n] = cnt;
  float inv = 1.f / (float)(cnt > 0 ? cnt : 1);
  pooled_x[n * 3 + 0] = sx * inv;
  pooled_x[n * 3 + 1] = sy * inv;
  pooled_x[n * 3 + 2] = sz * inv;
}

// ---- radial: MFMA einsum + MFMA rad_w GEMM ----
__global__ __launch_bounds__(256) void k_radial(
    const float* __restrict__ x, const float* __restrict__ attr, const float* __restrict__ cw,
    const int* __restrict__ row, const int* __restrict__ col,
    const __hip_bfloat16* __restrict__ wz_rad, const float* __restrict__ rad_b,
    __hip_bfloat16* __restrict__ radf,
    unsigned* __restrict__ cnt_row, unsigned* __restrict__ cnt_col, int Ee) {
  __shared__ __hip_bfloat16 sD[TE][16][32];    // distances, then M1 (Bt form) in-place
  __shared__ __hip_bfloat16 sAc[TE][16][32];   // Ac't[b][j] = attr_col[j][b]*cwc[j]
  __shared__ __hip_bfloat16 sAr[TE][16][32];   // Ar't[a][i] = attr_row[i][a]*cwr[i]
  __shared__ __hip_bfloat16 s_radA[8][16][32]; // radial fragment-blocked for big GEMM
  __shared__ float s_xr[TE][14][3], s_xc[TE][14][3];
  __shared__ float s_cwr[TE][14], s_cwc[TE][14];
  __shared__ float s_rn[TE];
  __shared__ int s_row[TE], s_col[TE];

  const int t = threadIdx.x;
  const int e0 = blockIdx.x * TE;
  const int ne = min(TE, Ee - e0);

  if (t < TE) {
    int e = e0 + min(t, ne - 1);
    s_row[t] = row[e];
    s_col[t] = col[e];
    if (t < ne) {
      atomicAdd(&cnt_row[s_row[t]], 1u);
      atomicAdd(&cnt_col[s_col[t]], 1u);
    }
  }
  __syncthreads();
  // phase 2: zero pad buffers + load x, cw
  for (int i = t; i < 4096; i += 256) {
    ((int*)sD)[i] = 0;
    ((int*)sAc)[i] = 0;
    ((int*)sAr)[i] = 0;
  }
  for (int i = t; i < TE * 42; i += 256) {
    int e = i / 42, r = i % 42;
    s_xr[e][r / 3][r % 3] = x[(size_t)s_row[e] * 42 + r];
    s_xc[e][r / 3][r % 3] = x[(size_t)s_col[e] * 42 + r];
  }
  for (int i = t; i < TE * 14; i += 256) {
    int e = i / 14, c = i % 14;
    s_cwr[e][c] = cw[(size_t)s_row[e] * 14 + c];
    s_cwc[e][c] = cw[(size_t)s_col[e] * 14 + c];
  }
  __syncthreads();
  // phase 3: distances + cw-scaled attr operands
  for (int i = t; i < TE * 196; i += 256) {
    int e = i / 196, r = i % 196, ci = r / 14, cj = r % 14;
    float dx = s_xr[e][ci][0] - s_xc[e][cj][0];
    float dy = s_xr[e][ci][1] - s_xc[e][cj][1];
    float dz = s_xr[e][ci][2] - s_xc[e][cj][2];
    sD[e][ci][cj] = __float2bfloat16(sqrtf(dx * dx + dy * dy + dz * dz));
  }
  for (int i = t; i < TE * 224; i += 256) {
    int e = i / 224, r = i % 224, c = r >> 4, a = r & 15;
    sAr[e][a][c] = __float2bfloat16(attr[(size_t)s_row[e] * 224 + r] * s_cwr[e][c]);
    sAc[e][a][c] = __float2bfloat16(attr[(size_t)s_col[e] * 224 + r] * s_cwc[e][c]);
  }
  __syncthreads();

  const int lane = t & 63, wave = t >> 6, quad = lane >> 4, mr = lane & 15;

  // phase 4: per-edge MFMA einsum (each wave owns 4 edges)
#pragma unroll
  for (int p = 0; p < 4; p++) {
    int e = wave * 4 + p;
    // M1 = D @ Ac'   (M=i, N=b, K=j)
    bf16x8 a1 = *(const bf16x8*)&sD[e][mr][quad * 8];
    bf16x8 b1 = *(const bf16x8*)&sAc[e][mr][quad * 8];
    f32x4 z = {0.f, 0.f, 0.f, 0.f};
    f32x4 m1 = __builtin_amdgcn_mfma_f32_16x16x32_bf16(a1, b1, z, 0, 0, 0);
    // write M1 into Bt form, in-place over D: sD[e][b=mr][i=quad*4+r]
#pragma unroll
    for (int r = 0; r < 4; r++)
      sD[e][mr][quad * 4 + r] = __float2bfloat16(m1[r]);
    // radial = Ar'^T @ M1   (M=a, N=b, K=i)
    bf16x8 a2 = *(const bf16x8*)&sAr[e][mr][quad * 8];
    bf16x8 b2 = *(const bf16x8*)&sD[e][mr][quad * 8];
    f32x4 rd = __builtin_amdgcn_mfma_f32_16x16x32_bf16(a2, b2, z, 0, 0, 0);
    float ss = 0.f;
#pragma unroll
    for (int r = 0; r < 4; r++) {
      int aa = quad * 4 + r;
      float v = rd[r];
      ss = fmaf(v, v, ss);
      s_radA[aa >> 1][e][(aa & 1) * 16 + mr] = __float2bfloat16(v);
    }
    ss += __shfl_xor(ss, 32);
    ss += __shfl_xor(ss, 16);
    ss += __shfl_xor(ss, 8);
    ss += __shfl_xor(ss, 4);
    ss += __shfl_xor(ss, 2);
    ss += __shfl_xor(ss, 1);
    if (lane == 0) s_rn[e] = sqrtf(ss) + 1.0f;
  }
  __syncthreads();
  // phase 5: radf = (radial @ rad_w + rad_b) / rn   (K=256)
  {
    const int n0 = wave * 32;
    f32x4 acc0 = {0.f, 0.f, 0.f, 0.f}, acc1 = {0.f, 0.f, 0.f, 0.f};
#pragma unroll
    for (int kb = 0; kb < 8; kb++) {
      bf16x8 a = *(const bf16x8*)&s_radA[kb][mr][quad * 8];
      const __hip_bfloat16* wp = wz_rad + ((size_t)(kb * 128 + n0 + mr) * 32 + quad * 8);
      bf16x8 b0 = *(const bf16x8*)wp;
      bf16x8 b1 = *(const bf16x8*)(wp + 16 * 32);
      acc0 = __builtin_amdgcn_mfma_f32_16x16x32_bf16(a, b0, acc0, 0, 0, 0);
      acc1 = __builtin_amdgcn_mfma_f32_16x16x32_bf16(a, b1, acc1, 0, 0, 0);
    }
    float bias0 = rad_b[n0 + mr], bias1 = rad_b[n0 + 16 + mr];
#pragma unroll
    for (int r = 0; r < 4; r++) {
      int e = quad * 4 + r;
      if (e < ne) {
        float inv = 1.f / s_rn[e];
        size_t base = (size_t)(e0 + e) * 128;
        radf[base + n0 + mr]      = __float2bfloat16((acc0[r] + bias0) * inv);
        radf[base + n0 + 16 + mr] = __float2bfloat16((acc1[r] + bias1) * inv);
      }
    }
  }
}

// ---- fused edge MLP chain (MFMA) + gate + RollerPooling + scatters ----
__global__ __launch_bounds__(256) void k_edge(
    const float* __restrict__ h, const float* __restrict__ x,
    const int* __restrict__ row, const int* __restrict__ col,
    const __hip_bfloat16* __restrict__ radf,
    const float* __restrict__ pooled_x, const int* __restrict__ chsum,
    const __hip_bfloat16* __restrict__ wz_e1, const float* __restrict__ e_b1,
    const __hip_bfloat16* __restrict__ wz_e2, const float* __restrict__ e_b2,
    const float* __restrict__ att_w, const float* __restrict__ att_b,
    const __hip_bfloat16* __restrict__ wz_c1, const float* __restrict__ c_b1,
    const float* __restrict__ c_w2, const float* __restrict__ c_b2,
    float* __restrict__ x_acc, float* __restrict__ agg, int Ee) {
  __shared__ __hip_bfloat16 sA[12][16][32];   // [h_row | h_col | radf], K=384
  __shared__ __hip_bfloat16 sT[4][16][32];    // ef1
  __shared__ __hip_bfloat16 sU[4][16][32];    // ef2 (ungated)
  __shared__ float sCmh[16][132];             // cmh fp32
  __shared__ float s_xr[TE][42];
  __shared__ float s_pc[TE][3];
  __shared__ float s_cm[TE][14];
  __shared__ float s_pool[TE][14];
  __shared__ float s_red[TE][16];
  __shared__ float s_att[TE];
  __shared__ int s_row[TE], s_col[TE], s_cs[TE];

  const int t = threadIdx.x;
  const int e0 = blockIdx.x * TE;
  const int ne = min(TE, Ee - e0);

  if (t < TE) {
    int e = e0 + min(t, ne - 1);
    s_row[t] = row[e];
    s_col[t] = col[e];
    s_cs[t] = chsum[s_row[t]];
  }
  __syncthreads();
  for (int i = t; i < TE * 64; i += 256) {
    int m = i >> 6, kp = (i & 63) << 1;
    int kb = kp >> 5, kk = kp & 31;
    const float2 hv = *(const float2*)&h[(size_t)s_row[m] * 128 + kp];
    sA[kb][m][kk]     = __float2bfloat16(hv.x);
    sA[kb][m][kk + 1] = __float2bfloat16(hv.y);
    const float2 cv = *(const float2*)&h[(size_t)s_col[m] * 128 + kp];
    sA[4 + kb][m][kk]     = __float2bfloat16(cv.x);
    sA[4 + kb][m][kk + 1] = __float2bfloat16(cv.y);
    int ge = e0 + min(m, ne - 1);
    const __hip_bfloat16* rp = &radf[(size_t)ge * 128 + kp];
    sA[8 + kb][m][kk]     = rp[0];
    sA[8 + kb][m][kk + 1] = rp[1];
  }
  for (int i = t; i < TE * 42; i += 256) {
    int e = i / 42, r = i % 42;
    s_xr[e][r] = x[(size_t)s_row[e] * 42 + r];
  }
  if (t < TE * 3) {
    int e = t / 3, d = t % 3;
    s_pc[e][d] = pooled_x[(size_t)s_col[e] * 3 + d];
  }
  __syncthreads();

  const int lane = t & 63, wave = t >> 6, quad = lane >> 4, mr = lane & 15;
  const int n0 = wave * 32;

  // stage 1: ef1 = silu(A @ e_w1 + e_b1), K=384
  {
    f32x4 acc0 = {0.f, 0.f, 0.f, 0.f}, acc1 = {0.f, 0.f, 0.f, 0.f};
#pragma unroll
    for (int kb = 0; kb < 12; kb++) {
      bf16x8 a = *(const bf16x8*)&sA[kb][mr][quad * 8];
      const __hip_bfloat16* wp = wz_e1 + ((size_t)(kb * 128 + n0 + mr) * 32 + quad * 8);
      bf16x8 b0 = *(const bf16x8*)wp;
      bf16x8 b1 = *(const bf16x8*)(wp + 16 * 32);
      acc0 = __builtin_amdgcn_mfma_f32_16x16x32_bf16(a, b0, acc0, 0, 0, 0);
      acc1 = __builtin_amdgcn_mfma_f32_16x16x32_bf16(a, b1, acc1, 0, 0, 0);
    }
    float bias0 = e_b1[n0 + mr], bias1 = e_b1[n0 + 16 + mr];
#pragma unroll
    for (int r = 0; r < 4; r++) {
      int e = quad * 4 + r;
      sT[wave][e][mr]      = __float2bfloat16(siluf(acc0[r] + bias0));
      sT[wave][e][16 + mr] = __float2bfloat16(siluf(acc1[r] + bias1));
    }
  }
  __syncthreads();
  // stage 2: ef2 = silu(ef1 @ e_w2 + e_b2), K=128
  {
    f32x4 acc0 = {0.f, 0.f, 0.f, 0.f}, acc1 = {0.f, 0.f, 0.f, 0.f};
#pragma unroll
    for (int kb = 0; kb < 4; kb++) {
      bf16x8 a = *(const bf16x8*)&sT[kb][mr][quad * 8];
      const __hip_bfloat16* wp = wz_e2 + ((size_t)(kb * 128 + n0 + mr) * 32 + quad * 8);
      bf16x8 b0 = *(const bf16x8*)wp;
      bf16x8 b1 = *(const bf16x8*)(wp + 16 * 32);
      acc0 = __builtin_amdgcn_mfma_f32_16x16x32_bf16(a, b0, acc0, 0, 0, 0);
      acc1 = __builtin_amdgcn_mfma_f32_16x16x32_bf16(a, b1, acc1, 0, 0, 0);
    }
    float bias0 = e_b2[n0 + mr], bias1 = e_b2[n0 + 16 + mr];
#pragma unroll
    for (int r = 0; r < 4; r++) {
      int e = quad * 4 + r;
      sU[wave][e][mr]      = __float2bfloat16(siluf(acc0[r] + bias0));
      sU[wave][e][16 + mr] = __float2bfloat16(siluf(acc1[r] + bias1));
    }
  }
  __syncthreads();
  // attention gate scalar per edge
  {
    int e = t >> 4, p = t & 15;
    float s = 0.f;
#pragma unroll
    for (int j = 0; j < 8; j++) {
      int k = p * 8 + j;
      s += __bfloat162float(sU[k >> 5][e][k & 31]) * att_w[k];
    }
    s_red[e][p] = s;
  }
  __syncthreads();
  if (t < TE) {
    float s = 0.f;
#pragma unroll
    for (int i = 0; i < 16; i++) s += s_red[t][i];
    s_att[t] = sigmf(s + att_b[0]);
  }
  __syncthreads();
  // stage 3: cmh = silu(att*(ef2 @ c_w1) + c_b1)
  {
    f32x4 acc0 = {0.f, 0.f, 0.f, 0.f}, acc1 = {0.f, 0.f, 0.f, 0.f};
#pragma unroll
    for (int kb = 0; kb < 4; kb++) {
      bf16x8 a = *(const bf16x8*)&sU[kb][mr][quad * 8];
      const __hip_bfloat16* wp = wz_c1 + ((size_t)(kb * 128 + n0 + mr) * 32 + quad * 8);
      bf16x8 b0 = *(const bf16x8*)wp;
      bf16x8 b1 = *(const bf16x8*)(wp + 16 * 32);
      acc0 = __builtin_amdgcn_mfma_f32_16x16x32_bf16(a, b0, acc0, 0, 0, 0);
      acc1 = __builtin_amdgcn_mfma_f32_16x16x32_bf16(a, b1, acc1, 0, 0, 0);
    }
    float bias0 = c_b1[n0 + mr], bias1 = c_b1[n0 + 16 + mr];
#pragma unroll
    for (int r = 0; r < 4; r++) {
      int e = quad * 4 + r;
      float av = s_att[e];
      sCmh[e][n0 + mr]      = siluf(av * acc0[r] + bias0);
      sCmh[e][n0 + 16 + mr] = siluf(av * acc1[r] + bias1);
    }
  }
  __syncthreads();
  // cm = cmh @ c_w2 + c_b2
  if (t < TE * 14) {
    int e = t / 14, c = t % 14;
    float acc = c_b2[c];
    for (int k = 0; k < 128; k++) acc += sCmh[e][k] * c_w2[k * 14 + c];
    s_cm[e][c] = acc;
  }
  __syncthreads();
  // RollerPooling
  if (t < TE * 14) {
    int e = t / 14, c = t % 14;
    int wsz = 15 - s_cs[e];
    int hi = min(c + wsz, 14);
    float s = 0.f;
    for (int j = c; j < hi; j++) s += s_cm[e][j];
    s_pool[e][c] = s / (float)wsz;
  }
  __syncthreads();
  // trans scatter
  for (int i = t; i < TE * 42; i += 256) {
    int e = i / 42, r = i % 42, c = r / 3, d = r % 3;
    if (e < ne) {
      float v = (s_xr[e][r] - s_pc[e][d]) * s_pool[e][c];
      unsafeAtomicAdd(&x_acc[(size_t)s_row[e] * 42 + r], v);
    }
  }
  // agg scatter (gated ef2)
  for (int i = t; i < TE * 128; i += 256) {
    int e = i >> 7, o = i & 127;
    if (e < ne) {
      float v = __bfloat162float(sU[o >> 5][e][o & 31]) * s_att[e];
      unsafeAtomicAdd(&agg[(size_t)s_col[e] * 128 + o], v);
    }
  }
}

// ---- node MLP (MFMA) + residual + LayerNorm ----
__global__ __launch_bounds__(256) void k_node(
    const float* __restrict__ h, const float* __restrict__ agg,
    const unsigned* __restrict__ cnt_col,
    const __hip_bfloat16* __restrict__ wz_n1, const float* __restrict__ n_b1,
    const __hip_bfloat16* __restrict__ wz_n2, const float* __restrict__ n_b2,
    const float* __restrict__ ln_g, const float* __restrict__ ln_b,
    float* __restrict__ out_h, int Nn) {
  __shared__ __hip_bfloat16 sA[8][16][32];   // [h | agg_mean], K=256
  __shared__ __hip_bfloat16 sT[4][16][32];   // hidden
  __shared__ float s_h[TN][128];
  __shared__ float s_o[TN][132];
  __shared__ float s_red[TN][16], s_mu[TN], s_rs[TN];
  const int t = threadIdx.x;
  const int nb0 = blockIdx.x * TN;
  const int nn = min(TN, Nn - nb0);

  for (int i = t; i < TN * 64; i += 256) {
    int m = i >> 6, kp = (i & 63) << 1;
    int kb = kp >> 5, kk = kp & 31;
    int gn = nb0 + min(m, nn - 1);
    const float2 hv = *(const float2*)&h[(size_t)gn * 128 + kp];
    sA[kb][m][kk]     = __float2bfloat16(hv.x);
    sA[kb][m][kk + 1] = __float2bfloat16(hv.y);
    s_h[m][kp]     = hv.x;
    s_h[m][kp + 1] = hv.y;
    unsigned c = cnt_col[gn];
    float inv = 1.f / (float)(c > 0 ? c : 1);
    const float2 gv = *(const float2*)&agg[(size_t)gn * 128 + kp];
    sA[4 + kb][m][kk]     = __float2bfloat16(gv.x * inv);
    sA[4 + kb][m][kk + 1] = __float2bfloat16(gv.y * inv);
  }
  __syncthreads();
  const int lane = t & 63, wave = t >> 6, quad = lane >> 4, mr = lane & 15;
  const int n0 = wave * 32;
  // stage 1: hidden = silu([h|agg] @ n_w1 + n_b1), K=256
  {
    f32x4 acc0 = {0.f, 0.f, 0.f, 0.f}, acc1 = {0.f, 0.f, 0.f, 0.f};
#pragma unroll
    for (int kb = 0; kb < 8; kb++) {
      bf16x8 a = *(const bf16x8*)&sA[kb][mr][quad * 8];
      const __hip_bfloat16* wp = wz_n1 + ((size_t)(kb * 128 + n0 + mr) * 32 + quad * 8);
      bf16x8 b0 = *(const bf16x8*)wp;
      bf16x8 b1 = *(const bf16x8*)(wp + 16 * 32);
      acc0 = __builtin_amdgcn_mfma_f32_16x16x32_bf16(a, b0, acc0, 0, 0, 0);
      acc1 = __builtin_amdgcn_mfma_f32_16x16x32_bf16(a, b1, acc1, 0, 0, 0);
    }
    float bias0 = n_b1[n0 + mr], bias1 = n_b1[n0 + 16 + mr];
#pragma unroll
    for (int r = 0; r < 4; r++) {
      int m = quad * 4 + r;
      sT[wave][m][mr]      = __float2bfloat16(siluf(acc0[r] + bias0));
      sT[wave][m][16 + mr] = __float2bfloat16(siluf(acc1[r] + bias1));
    }
  }
  __syncthreads();
  // stage 2: o = h + hidden @ n_w2 + n_b2, K=128
  {
    f32x4 acc0 = {0.f, 0.f, 0.f, 0.f}, acc1 = {0.f, 0.f, 0.f, 0.f};
#pragma unroll
    for (int kb = 0; kb < 4; kb++) {
      bf16x8 a = *(const bf16x8*)&sT[kb][mr][quad * 8];
      const __hip_bfloat16* wp = wz_n2 + ((size_t)(kb * 128 + n0 + mr) * 32 + quad * 8);
      bf16x8 b0 = *(const bf16x8*)wp;
      bf16x8 b1 = *(const bf16x8*)(wp + 16 * 32);
      acc0 = __builtin_amdgcn_mfma_f32_16x16x32_bf16(a, b0, acc0, 0, 0, 0);
      acc1 = __builtin_amdgcn_mfma_f32_16x16x32_bf16(a, b1, acc1, 0, 0, 0);
    }
    float bias0 = n_b2[n0 + mr], bias1 = n_b2[n0 + 16 + mr];
#pragma unroll
    for (int r = 0; r < 4; r++) {
      int m = quad * 4 + r;
      s_o[m][n0 + mr]      = s_h[m][n0 + mr] + acc0[r] + bias0;
      s_o[m][n0 + 16 + mr] = s_h[m][n0 + 16 + mr] + acc1[r] + bias1;
    }
  }
  __syncthreads();
  // LayerNorm
  {
    int n = t >> 4, p = t & 15;
    float s = 0.f;
#pragma unroll
    for (int j = 0; j < 8; j++) s += s_o[n][p * 8 + j];
    s_red[n][p] = s;
  }
  __syncthreads();
  if (t < TN) {
    float s = 0.f;
#pragma unroll
    for (int i = 0; i < 16; i++) s += s_red[t][i];
    s_mu[t] = s * (1.f / 128.f);
  }
  __syncthreads();
  {
    int n = t >> 4, p = t & 15;
    float mu = s_mu[n], s = 0.f;
#pragma unroll
    for (int j = 0; j < 8; j++) {
      float d = s_o[n][p * 8 + j] - mu;
      s += d * d;
    }
    s_red[n][p] = s;
  }
  __syncthreads();
  if (t < TN) {
    float s = 0.f;
#pragma unroll
    for (int i = 0; i < 16; i++) s += s_red[t][i];
    s_rs[t] = rsqrtf(s * (1.f / 128.f) + 1e-5f);
  }
  __syncthreads();
  for (int i = t; i < TN * 128; i += 256) {
    int n = i >> 7, k = i & 127;
    if (n < nn)
      out_h[(size_t)(nb0 + n) * 128 + k] = (s_o[n][k] - s_mu[n]) * s_rs[n] * ln_g[k] + ln_b[k];
  }
}

__global__ __launch_bounds__(256) void k_xnew(const float* __restrict__ x,
                                              const float* __restrict__ x_acc,
                                              const unsigned* __restrict__ cnt_row,
                                              float* __restrict__ out_x, int Nn) {
  int i = blockIdx.x * 256 + threadIdx.x;
  int total = Nn * 42;
  if (i >= total) return;
  int n = i / 42;
  unsigned c = cnt_row[n];
  out_x[i] = x[i] + x_acc[i] / (float)(c > 0 ? c : 1);
}

extern "C" void kernel_launch(void* const* d_in, const int* in_sizes, int n_in,
                              void* d_out, int out_size, void* d_ws, size_t ws_size,
                              hipStream_t stream) {
  const float* h     = (const float*)d_in[0];
  const float* x     = (const float*)d_in[1];
  const float* attr  = (const float*)d_in[2];
  const float* cw    = (const float*)d_in[3];
  const int*   row   = (const int*)d_in[4];
  const int*   col   = (const int*)d_in[5];
  const float* rad_w = (const float*)d_in[6];
  const float* rad_b = (const float*)d_in[7];
  const float* e_w1  = (const float*)d_in[8];
  const float* e_b1  = (const float*)d_in[9];
  const float* e_w2  = (const float*)d_in[10];
  const float* e_b2  = (const float*)d_in[11];
  const float* att_w = (const float*)d_in[12];
  const float* att_b = (const float*)d_in[13];
  const float* c_w1  = (const float*)d_in[14];
  const float* c_b1  = (const float*)d_in[15];
  const float* c_w2  = (const float*)d_in[16];
  const float* c_b2  = (const float*)d_in[17];
  const float* n_w1  = (const float*)d_in[18];
  const float* n_b1  = (const float*)d_in[19];
  const float* n_w2  = (const float*)d_in[20];
  const float* n_b2  = (const float*)d_in[21];
  const float* ln_g  = (const float*)d_in[22];
  const float* ln_b  = (const float*)d_in[23];

  const int N = in_sizes[0] / 128;
  const int E = in_sizes[4];

  char* ws = (char*)d_ws;
  size_t off = 0;
  auto alloc = [&](size_t bytes) {
    size_t o = off;
    off += (bytes + 255) & ~(size_t)255;
    return o;
  };
  size_t off_radf = alloc((size_t)E * 128 * sizeof(__hip_bfloat16));
  size_t off_wzr  = alloc(32768 * sizeof(__hip_bfloat16));
  size_t off_wz1  = alloc(49152 * sizeof(__hip_bfloat16));
  size_t off_wz2  = alloc(16384 * sizeof(__hip_bfloat16));
  size_t off_wzc  = alloc(16384 * sizeof(__hip_bfloat16));
  size_t off_wzn1 = alloc(32768 * sizeof(__hip_bfloat16));
  size_t off_wzn2 = alloc(16384 * sizeof(__hip_bfloat16));
  size_t off_px   = alloc((size_t)N * 3 * sizeof(float));
  size_t off_cs   = alloc((size_t)N * sizeof(int));
  size_t off_cntr = alloc((size_t)N * sizeof(unsigned));
  size_t off_cntc = alloc((size_t)N * sizeof(unsigned));
  size_t off_xacc = alloc((size_t)N * 42 * sizeof(float));
  size_t off_agg  = alloc((size_t)N * 128 * sizeof(float));

  __hip_bfloat16* radf   = (__hip_bfloat16*)(ws + off_radf);
  __hip_bfloat16* wz_rad = (__hip_bfloat16*)(ws + off_wzr);
  __hip_bfloat16* wz_e1  = (__hip_bfloat16*)(ws + off_wz1);
  __hip_bfloat16* wz_e2  = (__hip_bfloat16*)(ws + off_wz2);
  __hip_bfloat16* wz_c1  = (__hip_bfloat16*)(ws + off_wzc);
  __hip_bfloat16* wz_n1  = (__hip_bfloat16*)(ws + off_wzn1);
  __hip_bfloat16* wz_n2  = (__hip_bfloat16*)(ws + off_wzn2);
  float* pooled_x  = (float*)(ws + off_px);
  int* chsum       = (int*)(ws + off_cs);
  unsigned* cnt_row = (unsigned*)(ws + off_cntr);
  unsigned* cnt_col = (unsigned*)(ws + off_cntc);
  float* x_acc     = (float*)(ws + off_xacc);
  float* agg       = (float*)(ws + off_agg);

  hipMemsetAsync(ws + off_cntr, 0, off - off_cntr, stream);

  k_wswz<<<dim3((163840 + 255) / 256), dim3(256), 0, stream>>>(
      rad_w, e_w1, e_w2, c_w1, n_w1, n_w2,
      wz_rad, wz_e1, wz_e2, wz_c1, wz_n1, wz_n2);
  k_prep<<<dim3((N + 255) / 256), dim3(256), 0, stream>>>(x, cw, pooled_x, chsum, N);
  k_radial<<<dim3((E + TE - 1) / TE), dim3(256), 0, stream>>>(
      x, attr, cw, row, col, wz_rad, rad_b, radf, cnt_row, cnt_col, E);
  k_edge<<<dim3((E + TE - 1) / TE), dim3(256), 0, stream>>>(
      h, x, row, col, radf, pooled_x, chsum,
      wz_e1, e_b1, wz_e2, e_b2, att_w, att_b, wz_c1, c_b1, c_w2, c_b2,
      x_acc, agg, E);
  k_node<<<dim3((N + TN - 1) / TN), dim3(256), 0, stream>>>(
      h, agg, cnt_col, wz_n1, n_b1, wz_n2, n_b2, ln_g, ln_b, (float*)d_out, N);
  k_xnew<<<dim3((N * 42 + 255) / 256), dim3(256), 0, stream>>>(
      x, x_acc, cnt_row, (float*)d_out + (size_t)N * 128, N);
}

// Round 4
// 456.449 us; speedup vs baseline: 3.8382x; 1.7204x over previous
//
#include <hip/hip_runtime.h>
#include <hip/hip_bf16.h>

// EnhancedGNNEncoder round 4: merged radial+edge megakernel.
//  - coord2radial einsum inputs assembled IN REGISTERS (shfl + direct frag-order
//    global gathers), M1 redistributed between the two per-edge MFMAs via shfl.
//  - radf never touches global: rad_w GEMM writes straight into the sA K-tiles.
//  - LDS fragment tiles padded to 40 shorts (80B rows, kills 8-way b128 bank
//    conflicts) and aliased (sT/sV and sU overlay the dead sRad) -> ~32 KB LDS,
//    __launch_bounds__(256,4) -> 4 blocks/CU (16 waves, 2x round-3 occupancy).
// MFMA 16x16x32: A[m=lane&15][k=quad*8+j], B[k=quad*8+j][n=lane&15],
//                D col=lane&15, row=quad*4+reg.

#define TE 16
#define TN 16
#define PAD 40

typedef __attribute__((ext_vector_type(8))) short bf16x8;
typedef __attribute__((ext_vector_type(4))) float f32x4;

__device__ __forceinline__ float siluf(float v) { return v / (1.f + __expf(-v)); }
__device__ __forceinline__ float sigmf(float v) { return 1.f / (1.f + __expf(-v)); }
__device__ __forceinline__ short f2bs(float f) {
  union { __hip_bfloat16 b; short s; } u;
  u.b = __float2bfloat16(f);
  return u.s;
}

// ---- weight swizzle: fp32 [K][N] -> bf16 B-frag [K/32][N][32] ----
__global__ __launch_bounds__(256) void k_wswz(
    const float* __restrict__ rad_w, const float* __restrict__ e_w1,
    const float* __restrict__ e_w2, const float* __restrict__ c_w1,
    const float* __restrict__ n_w1, const float* __restrict__ n_w2,
    const float* __restrict__ c_w2,
    __hip_bfloat16* __restrict__ wz_rad, __hip_bfloat16* __restrict__ wz_e1,
    __hip_bfloat16* __restrict__ wz_e2, __hip_bfloat16* __restrict__ wz_c1,
    __hip_bfloat16* __restrict__ wz_n1, __hip_bfloat16* __restrict__ wz_n2,
    __hip_bfloat16* __restrict__ wz_c2) {
  int i = blockIdx.x * 256 + threadIdx.x;
  if (i >= 165888) return;
  if (i >= 163840) {  // c_w2: [128][14] -> [4][16][32], n=14,15 zero
    int base = i - 163840;
    int k = base >> 4, n = base & 15;
    wz_c2[(size_t)(k >> 5) * 512 + n * 32 + (k & 31)] =
        (n < 14) ? __float2bfloat16(c_w2[k * 14 + n]) : __float2bfloat16(0.f);
    return;
  }
  const float* W;
  __hip_bfloat16* O;
  int base;
  if (i < 32768) { W = rad_w; O = wz_rad; base = i; }
  else if (i < 81920) { W = e_w1; O = wz_e1; base = i - 32768; }
  else if (i < 98304) { W = e_w2; O = wz_e2; base = i - 81920; }
  else if (i < 114688) { W = c_w1; O = wz_c1; base = i - 98304; }
  else if (i < 147456) { W = n_w1; O = wz_n1; base = i - 114688; }
  else { W = n_w2; O = wz_n2; base = i - 147456; }
  int k = base >> 7, n = base & 127;
  O[(size_t)((k >> 5) * 128 + n) * 32 + (k & 31)] = __float2bfloat16(W[base]);
}

// ---- per-node prep ----
__global__ __launch_bounds__(256) void k_prep(const float* __restrict__ x,
                                              const float* __restrict__ cw,
                                              float* __restrict__ pooled_x,
                                              int* __restrict__ chsum, int Nn) {
  int n = blockIdx.x * 256 + threadIdx.x;
  if (n >= Nn) return;
  int cnt = 0;
  float sx = 0.f, sy = 0.f, sz = 0.f;
#pragma unroll
  for (int c = 0; c < 14; c++) {
    float w = cw[n * 14 + c];
    if (w != 0.f) {
      cnt++;
      sx += x[n * 42 + c * 3 + 0];
      sy += x[n * 42 + c * 3 + 1];
      sz += x[n * 42 + c * 3 + 2];
    }
  }
  chsum[n] = cnt;
  float inv = 1.f / (float)(cnt > 0 ? cnt : 1);
  pooled_x[n * 3 + 0] = sx * inv;
  pooled_x[n * 3 + 1] = sy * inv;
  pooled_x[n * 3 + 2] = sz * inv;
}

// ---- merged: radial einsum + rad GEMM + edge MLP + gate + roller + scatters ----
__global__ __launch_bounds__(256, 4) void k_edge(
    const float* __restrict__ h, const float* __restrict__ x,
    const float* __restrict__ attr, const float* __restrict__ cw,
    const int* __restrict__ row, const int* __restrict__ col,
    const float* __restrict__ pooled_x, const int* __restrict__ chsum,
    const __hip_bfloat16* __restrict__ wz_rad, const float* __restrict__ rad_b,
    const __hip_bfloat16* __restrict__ wz_e1, const float* __restrict__ e_b1,
    const __hip_bfloat16* __restrict__ wz_e2, const float* __restrict__ e_b2,
    const float* __restrict__ att_w, const float* __restrict__ att_b,
    const __hip_bfloat16* __restrict__ wz_c1, const float* __restrict__ c_b1,
    const __hip_bfloat16* __restrict__ wz_c2, const float* __restrict__ c_b2,
    unsigned* __restrict__ cnt_row, unsigned* __restrict__ cnt_col,
    float* __restrict__ x_acc, float* __restrict__ agg, int Ee) {
  __shared__ __hip_bfloat16 sA[12][16][PAD];  // [h_row | h_col | radf] K=384
  __shared__ __hip_bfloat16 sW[8][16][PAD];   // sRad / later sT(0..3),sU(4..7),sV(0..3)
  __shared__ float s_xr[TE][42];
  __shared__ float s_pc[TE][3];
  __shared__ float s_cm[TE][14];
  __shared__ float s_pool[TE][14];
  __shared__ float s_att[TE], s_rn[TE];
  __shared__ int s_row[TE], s_col[TE], s_cs[TE];

  const int t = threadIdx.x;
  const int e0 = blockIdx.x * TE;
  const int ne = min(TE, Ee - e0);

  if (t < TE) {
    int e = e0 + min(t, ne - 1);
    s_row[t] = row[e];
    s_col[t] = col[e];
    s_cs[t] = chsum[s_row[t]];
    if (t < ne) {
      atomicAdd(&cnt_row[s_row[t]], 1u);
      atomicAdd(&cnt_col[s_col[t]], 1u);
    }
  }
  __syncthreads();

  // h staging -> sA[0..7]  (long-latency; issue before einsum compute)
  for (int i = t; i < TE * 64; i += 256) {
    int m = i >> 6, kp = (i & 63) << 1;
    int kb = kp >> 5, kk = kp & 31;
    const float2 hv = *(const float2*)&h[(size_t)s_row[m] * 128 + kp];
    sA[kb][m][kk]     = __float2bfloat16(hv.x);
    sA[kb][m][kk + 1] = __float2bfloat16(hv.y);
    const float2 cv = *(const float2*)&h[(size_t)s_col[m] * 128 + kp];
    sA[4 + kb][m][kk]     = __float2bfloat16(cv.x);
    sA[4 + kb][m][kk + 1] = __float2bfloat16(cv.y);
  }
  if (t < TE * 3) {
    int e = t / 3, d = t % 3;
    s_pc[e][d] = pooled_x[(size_t)s_col[e] * 3 + d];
  }

  const int lane = t & 63, wave = t >> 6, quad = lane >> 4, mr = lane & 15;

  // ---- einsum: each wave owns 4 edges, all inputs in registers ----
  f32x4 zacc = {0.f, 0.f, 0.f, 0.f};
#pragma unroll
  for (int p = 0; p < 4; p++) {
    const int e = wave * 4 + p;
    const int re = s_row[e], ce = s_col[e];
    float xr0 = 0.f, xr1 = 0.f, xr2 = 0.f, xc0 = 0.f, xc1 = 0.f, xc2 = 0.f;
    float cwrv = 0.f, cwcv = 0.f;
    if (mr < 14) {
      const float* xp = x + (size_t)re * 42 + mr * 3;
      xr0 = xp[0]; xr1 = xp[1]; xr2 = xp[2];
      const float* xq = x + (size_t)ce * 42 + mr * 3;
      xc0 = xq[0]; xc1 = xq[1]; xc2 = xq[2];
      cwrv = cw[(size_t)re * 14 + mr];
      cwcv = cw[(size_t)ce * 14 + mr];
    }
    if (quad == 0 && mr < 14) {
      s_xr[e][mr * 3 + 0] = xr0;
      s_xr[e][mr * 3 + 1] = xr1;
      s_xr[e][mr * 3 + 2] = xr2;
    }
    bf16x8 aD, bC;
#pragma unroll
    for (int j = 0; j < 8; j++) {
      const int k = quad * 8 + j;
      float bx = __shfl(xc0, k), by = __shfl(xc1, k), bz = __shfl(xc2, k);
      float cwk = __shfl(cwcv, k);
      float dx = xr0 - bx, dy = xr1 - by, dz = xr2 - bz;
      float dist = (k < 14 && mr < 14) ? sqrtf(dx * dx + dy * dy + dz * dz) : 0.f;
      aD[j] = f2bs(dist);
      float av = (k < 14) ? attr[(size_t)ce * 224 + k * 16 + mr] : 0.f;
      bC[j] = f2bs(av * cwk);
    }
    f32x4 m1 = __builtin_amdgcn_mfma_f32_16x16x32_bf16(aD, bC, zacc, 0, 0, 0);
    bf16x8 bM, aR;
#pragma unroll
    for (int j = 0; j < 8; j++) {
      const int qs = (quad * 2 + (j >> 2)) & 3;     // wraps for quad>=2 (masked)
      float mv = __shfl(m1[j & 3], (qs << 4) | mr);
      if (quad >= 2) mv = 0.f;                       // M1 rows >=16 are zero-pad
      bM[j] = f2bs(mv);
      const int ii = quad * 8 + j;
      float cwk = __shfl(cwrv, ii);
      float av = (ii < 14) ? attr[(size_t)re * 224 + ii * 16 + mr] : 0.f;
      aR[j] = f2bs(av * cwk);
    }
    f32x4 rd = __builtin_amdgcn_mfma_f32_16x16x32_bf16(aR, bM, zacc, 0, 0, 0);
    float ss = rd[0] * rd[0] + rd[1] * rd[1] + rd[2] * rd[2] + rd[3] * rd[3];
    ss += __shfl_xor(ss, 32); ss += __shfl_xor(ss, 16); ss += __shfl_xor(ss, 8);
    ss += __shfl_xor(ss, 4);  ss += __shfl_xor(ss, 2);  ss += __shfl_xor(ss, 1);
    if (lane == 0) s_rn[e] = sqrtf(ss) + 1.0f;
#pragma unroll
    for (int r = 0; r < 4; r++) {
      const int aa = quad * 4 + r;                   // radial row a
      sW[aa >> 1][e][((aa & 1) << 4) | mr] = __float2bfloat16(rd[r]);
    }
  }
  __syncthreads();

  const int n0 = wave * 32;
  // ---- rad GEMM: radf = (radial @ rad_w + rad_b)/rn -> sA[8..11] ----
  {
    f32x4 acc0 = zacc, acc1 = zacc;
#pragma unroll
    for (int kb = 0; kb < 8; kb++) {
      bf16x8 a = *(const bf16x8*)&sW[kb][mr][quad * 8];
      const __hip_bfloat16* wp = wz_rad + ((size_t)(kb * 128 + n0 + mr) * 32 + quad * 8);
      bf16x8 b0 = *(const bf16x8*)wp;
      bf16x8 b1 = *(const bf16x8*)(wp + 16 * 32);
      acc0 = __builtin_amdgcn_mfma_f32_16x16x32_bf16(a, b0, acc0, 0, 0, 0);
      acc1 = __builtin_amdgcn_mfma_f32_16x16x32_bf16(a, b1, acc1, 0, 0, 0);
    }
    float bias0 = rad_b[n0 + mr], bias1 = rad_b[n0 + 16 + mr];
#pragma unroll
    for (int r = 0; r < 4; r++) {
      int e = quad * 4 + r;
      float inv = 1.f / s_rn[e];
      sA[8 + wave][e][mr]      = __float2bfloat16((acc0[r] + bias0) * inv);
      sA[8 + wave][e][16 + mr] = __float2bfloat16((acc1[r] + bias1) * inv);
    }
  }
  __syncthreads();
  // ---- stage 1: ef1 = silu(A @ e_w1 + e_b1), K=384 -> sT (=sW[0..3]) ----
  {
    f32x4 acc0 = zacc, acc1 = zacc;
#pragma unroll
    for (int kb = 0; kb < 12; kb++) {
      bf16x8 a = *(const bf16x8*)&sA[kb][mr][quad * 8];
      const __hip_bfloat16* wp = wz_e1 + ((size_t)(kb * 128 + n0 + mr) * 32 + quad * 8);
      bf16x8 b0 = *(const bf16x8*)wp;
      bf16x8 b1 = *(const bf16x8*)(wp + 16 * 32);
      acc0 = __builtin_amdgcn_mfma_f32_16x16x32_bf16(a, b0, acc0, 0, 0, 0);
      acc1 = __builtin_amdgcn_mfma_f32_16x16x32_bf16(a, b1, acc1, 0, 0, 0);
    }
    float bias0 = e_b1[n0 + mr], bias1 = e_b1[n0 + 16 + mr];
#pragma unroll
    for (int r = 0; r < 4; r++) {
      int e = quad * 4 + r;
      sW[wave][e][mr]      = __float2bfloat16(siluf(acc0[r] + bias0));
      sW[wave][e][16 + mr] = __float2bfloat16(siluf(acc1[r] + bias1));
    }
  }
  __syncthreads();
  // ---- stage 2: ef2 = silu(ef1 @ e_w2 + e_b2) -> sU (=sW[4..7]) ----
  {
    f32x4 acc0 = zacc, acc1 = zacc;
#pragma unroll
    for (int kb = 0; kb < 4; kb++) {
      bf16x8 a = *(const bf16x8*)&sW[kb][mr][quad * 8];
      const __hip_bfloat16* wp = wz_e2 + ((size_t)(kb * 128 + n0 + mr) * 32 + quad * 8);
      bf16x8 b0 = *(const bf16x8*)wp;
      bf16x8 b1 = *(const bf16x8*)(wp + 16 * 32);
      acc0 = __builtin_amdgcn_mfma_f32_16x16x32_bf16(a, b0, acc0, 0, 0, 0);
      acc1 = __builtin_amdgcn_mfma_f32_16x16x32_bf16(a, b1, acc1, 0, 0, 0);
    }
    float bias0 = e_b2[n0 + mr], bias1 = e_b2[n0 + 16 + mr];
#pragma unroll
    for (int r = 0; r < 4; r++) {
      int e = quad * 4 + r;
      sW[4 + wave][e][mr]      = __float2bfloat16(siluf(acc0[r] + bias0));
      sW[4 + wave][e][16 + mr] = __float2bfloat16(siluf(acc1[r] + bias1));
    }
  }
  __syncthreads();
  // ---- attention gate: in-wave shfl reduction (threads e*16+p share a wave) ----
  {
    int e = t >> 4, p = t & 15;
    float s = 0.f;
#pragma unroll
    for (int j = 0; j < 8; j++) {
      int k = p * 8 + j;
      s += __bfloat162float(sW[4 + (k >> 5)][e][k & 31]) * att_w[k];
    }
    s += __shfl_xor(s, 8); s += __shfl_xor(s, 4);
    s += __shfl_xor(s, 2); s += __shfl_xor(s, 1);
    if (p == 0) s_att[e] = sigmf(s + att_b[0]);
  }
  __syncthreads();
  // ---- stage 3: cmh = silu(att*(ef2 @ c_w1) + c_b1) -> sV (=sW[0..3]) ----
  {
    f32x4 acc0 = zacc, acc1 = zacc;
#pragma unroll
    for (int kb = 0; kb < 4; kb++) {
      bf16x8 a = *(const bf16x8*)&sW[4 + kb][mr][quad * 8];
      const __hip_bfloat16* wp = wz_c1 + ((size_t)(kb * 128 + n0 + mr) * 32 + quad * 8);
      bf16x8 b0 = *(const bf16x8*)wp;
      bf16x8 b1 = *(const bf16x8*)(wp + 16 * 32);
      acc0 = __builtin_amdgcn_mfma_f32_16x16x32_bf16(a, b0, acc0, 0, 0, 0);
      acc1 = __builtin_amdgcn_mfma_f32_16x16x32_bf16(a, b1, acc1, 0, 0, 0);
    }
    float bias0 = c_b1[n0 + mr], bias1 = c_b1[n0 + 16 + mr];
#pragma unroll
    for (int r = 0; r < 4; r++) {
      int e = quad * 4 + r;
      float av = s_att[e];
      sW[wave][e][mr]      = __float2bfloat16(siluf(av * acc0[r] + bias0));
      sW[wave][e][16 + mr] = __float2bfloat16(siluf(av * acc1[r] + bias1));
    }
  }
  __syncthreads();
  // ---- cm = cmh @ c_w2 + c_b2 via MFMA (wave 0 only) ----
  if (wave == 0) {
    f32x4 acc = zacc;
#pragma unroll
    for (int kb = 0; kb < 4; kb++) {
      bf16x8 a = *(const bf16x8*)&sW[kb][mr][quad * 8];
      bf16x8 b = *(const bf16x8*)(wz_c2 + ((size_t)(kb * 16 + mr) * 32 + quad * 8));
      acc = __builtin_amdgcn_mfma_f32_16x16x32_bf16(a, b, acc, 0, 0, 0);
    }
    if (mr < 14) {
      float bias = c_b2[mr];
#pragma unroll
      for (int r = 0; r < 4; r++) s_cm[quad * 4 + r][mr] = acc[r] + bias;
    }
  }
  __syncthreads();
  // ---- RollerPooling ----
  if (t < TE * 14) {
    int e = t / 14, c = t % 14;
    int wsz = 15 - s_cs[e];
    int hi = min(c + wsz, 14);
    float s = 0.f;
    for (int j = c; j < hi; j++) s += s_cm[e][j];
    s_pool[e][c] = s / (float)wsz;
  }
  __syncthreads();
  // ---- trans scatter ----
  for (int i = t; i < TE * 42; i += 256) {
    int e = i / 42, r = i % 42, c = r / 3, d = r % 3;
    if (e < ne) {
      float v = (s_xr[e][r] - s_pc[e][d]) * s_pool[e][c];
      unsafeAtomicAdd(&x_acc[(size_t)s_row[e] * 42 + r], v);
    }
  }
  // ---- agg scatter (gated ef2) ----
  for (int i = t; i < TE * 128; i += 256) {
    int e = i >> 7, o = i & 127;
    if (e < ne) {
      float v = __bfloat162float(sW[4 + (o >> 5)][e][o & 31]) * s_att[e];
      unsafeAtomicAdd(&agg[(size_t)s_col[e] * 128 + o], v);
    }
  }
}

// ---- node MLP (MFMA) + residual + LayerNorm ----
__global__ __launch_bounds__(256) void k_node(
    const float* __restrict__ h, const float* __restrict__ agg,
    const unsigned* __restrict__ cnt_col,
    const __hip_bfloat16* __restrict__ wz_n1, const float* __restrict__ n_b1,
    const __hip_bfloat16* __restrict__ wz_n2, const float* __restrict__ n_b2,
    const float* __restrict__ ln_g, const float* __restrict__ ln_b,
    float* __restrict__ out_h, int Nn) {
  __shared__ __hip_bfloat16 sA[8][16][PAD];
  __shared__ __hip_bfloat16 sT[4][16][PAD];
  __shared__ float s_h[TN][128];
  __shared__ float s_o[TN][132];
  __shared__ float s_red[TN][16], s_mu[TN], s_rs[TN];
  const int t = threadIdx.x;
  const int nb0 = blockIdx.x * TN;
  const int nn = min(TN, Nn - nb0);

  for (int i = t; i < TN * 64; i += 256) {
    int m = i >> 6, kp = (i & 63) << 1;
    int kb = kp >> 5, kk = kp & 31;
    int gn = nb0 + min(m, nn - 1);
    const float2 hv = *(const float2*)&h[(size_t)gn * 128 + kp];
    sA[kb][m][kk]     = __float2bfloat16(hv.x);
    sA[kb][m][kk + 1] = __float2bfloat16(hv.y);
    s_h[m][kp]     = hv.x;
    s_h[m][kp + 1] = hv.y;
    unsigned c = cnt_col[gn];
    float inv = 1.f / (float)(c > 0 ? c : 1);
    const float2 gv = *(const float2*)&agg[(size_t)gn * 128 + kp];
    sA[4 + kb][m][kk]     = __float2bfloat16(gv.x * inv);
    sA[4 + kb][m][kk + 1] = __float2bfloat16(gv.y * inv);
  }
  __syncthreads();
  const int lane = t & 63, wave = t >> 6, quad = lane >> 4, mr = lane & 15;
  const int n0 = wave * 32;
  f32x4 zacc = {0.f, 0.f, 0.f, 0.f};
  {
    f32x4 acc0 = zacc, acc1 = zacc;
#pragma unroll
    for (int kb = 0; kb < 8; kb++) {
      bf16x8 a = *(const bf16x8*)&sA[kb][mr][quad * 8];
      const __hip_bfloat16* wp = wz_n1 + ((size_t)(kb * 128 + n0 + mr) * 32 + quad * 8);
      bf16x8 b0 = *(const bf16x8*)wp;
      bf16x8 b1 = *(const bf16x8*)(wp + 16 * 32);
      acc0 = __builtin_amdgcn_mfma_f32_16x16x32_bf16(a, b0, acc0, 0, 0, 0);
      acc1 = __builtin_amdgcn_mfma_f32_16x16x32_bf16(a, b1, acc1, 0, 0, 0);
    }
    float bias0 = n_b1[n0 + mr], bias1 = n_b1[n0 + 16 + mr];
#pragma unroll
    for (int r = 0; r < 4; r++) {
      int m = quad * 4 + r;
      sT[wave][m][mr]      = __float2bfloat16(siluf(acc0[r] + bias0));
      sT[wave][m][16 + mr] = __float2bfloat16(siluf(acc1[r] + bias1));
    }
  }
  __syncthreads();
  {
    f32x4 acc0 = zacc, acc1 = zacc;
#pragma unroll
    for (int kb = 0; kb < 4; kb++) {
      bf16x8 a = *(const bf16x8*)&sT[kb][mr][quad * 8];
      const __hip_bfloat16* wp = wz_n2 + ((size_t)(kb * 128 + n0 + mr) * 32 + quad * 8);
      bf16x8 b0 = *(const bf16x8*)wp;
      bf16x8 b1 = *(const bf16x8*)(wp + 16 * 32);
      acc0 = __builtin_amdgcn_mfma_f32_16x16x32_bf16(a, b0, acc0, 0, 0, 0);
      acc1 = __builtin_amdgcn_mfma_f32_16x16x32_bf16(a, b1, acc1, 0, 0, 0);
    }
    float bias0 = n_b2[n0 + mr], bias1 = n_b2[n0 + 16 + mr];
#pragma unroll
    for (int r = 0; r < 4; r++) {
      int m = quad * 4 + r;
      s_o[m][n0 + mr]      = s_h[m][n0 + mr] + acc0[r] + bias0;
      s_o[m][n0 + 16 + mr] = s_h[m][n0 + 16 + mr] + acc1[r] + bias1;
    }
  }
  __syncthreads();
  {
    int n = t >> 4, p = t & 15;
    float s = 0.f;
#pragma unroll
    for (int j = 0; j < 8; j++) s += s_o[n][p * 8 + j];
    s_red[n][p] = s;
  }
  __syncthreads();
  if (t < TN) {
    float s = 0.f;
#pragma unroll
    for (int i = 0; i < 16; i++) s += s_red[t][i];
    s_mu[t] = s * (1.f / 128.f);
  }
  __syncthreads();
  {
    int n = t >> 4, p = t & 15;
    float mu = s_mu[n], s = 0.f;
#pragma unroll
    for (int j = 0; j < 8; j++) {
      float d = s_o[n][p * 8 + j] - mu;
      s += d * d;
    }
    s_red[n][p] = s;
  }
  __syncthreads();
  if (t < TN) {
    float s = 0.f;
#pragma unroll
    for (int i = 0; i < 16; i++) s += s_red[t][i];
    s_rs[t] = rsqrtf(s * (1.f / 128.f) + 1e-5f);
  }
  __syncthreads();
  for (int i = t; i < TN * 128; i += 256) {
    int n = i >> 7, k = i & 127;
    if (n < nn)
      out_h[(size_t)(nb0 + n) * 128 + k] = (s_o[n][k] - s_mu[n]) * s_rs[n] * ln_g[k] + ln_b[k];
  }
}

__global__ __launch_bounds__(256) void k_xnew(const float* __restrict__ x,
                                              const float* __restrict__ x_acc,
                                              const unsigned* __restrict__ cnt_row,
                                              float* __restrict__ out_x, int Nn) {
  int i = blockIdx.x * 256 + threadIdx.x;
  int total = Nn * 42;
  if (i >= total) return;
  int n = i / 42;
  unsigned c = cnt_row[n];
  out_x[i] = x[i] + x_acc[i] / (float)(c > 0 ? c : 1);
}

extern "C" void kernel_launch(void* const* d_in, const int* in_sizes, int n_in,
                              void* d_out, int out_size, void* d_ws, size_t ws_size,
                              hipStream_t stream) {
  const float* h     = (const float*)d_in[0];
  const float* x     = (const float*)d_in[1];
  const float* attr  = (const float*)d_in[2];
  const float* cw    = (const float*)d_in[3];
  const int*   row   = (const int*)d_in[4];
  const int*   col   = (const int*)d_in[5];
  const float* rad_w = (const float*)d_in[6];
  const float* rad_b = (const float*)d_in[7];
  const float* e_w1  = (const float*)d_in[8];
  const float* e_b1  = (const float*)d_in[9];
  const float* e_w2  = (const float*)d_in[10];
  const float* e_b2  = (const float*)d_in[11];
  const float* att_w = (const float*)d_in[12];
  const float* att_b = (const float*)d_in[13];
  const float* c_w1  = (const float*)d_in[14];
  const float* c_b1  = (const float*)d_in[15];
  const float* c_w2  = (const float*)d_in[16];
  const float* c_b2  = (const float*)d_in[17];
  const float* n_w1  = (const float*)d_in[18];
  const float* n_b1  = (const float*)d_in[19];
  const float* n_w2  = (const float*)d_in[20];
  const float* n_b2  = (const float*)d_in[21];
  const float* ln_g  = (const float*)d_in[22];
  const float* ln_b  = (const float*)d_in[23];

  const int N = in_sizes[0] / 128;
  const int E = in_sizes[4];

  char* ws = (char*)d_ws;
  size_t off = 0;
  auto alloc = [&](size_t bytes) {
    size_t o = off;
    off += (bytes + 255) & ~(size_t)255;
    return o;
  };
  size_t off_wzr  = alloc(32768 * sizeof(__hip_bfloat16));
  size_t off_wz1  = alloc(49152 * sizeof(__hip_bfloat16));
  size_t off_wz2  = alloc(16384 * sizeof(__hip_bfloat16));
  size_t off_wzc  = alloc(16384 * sizeof(__hip_bfloat16));
  size_t off_wzn1 = alloc(32768 * sizeof(__hip_bfloat16));
  size_t off_wzn2 = alloc(16384 * sizeof(__hip_bfloat16));
  size_t off_wzc2 = alloc(2048 * sizeof(__hip_bfloat16));
  size_t off_px   = alloc((size_t)N * 3 * sizeof(float));
  size_t off_cs   = alloc((size_t)N * sizeof(int));
  size_t off_cntr = alloc((size_t)N * sizeof(unsigned));
  size_t off_cntc = alloc((size_t)N * sizeof(unsigned));
  size_t off_xacc = alloc((size_t)N * 42 * sizeof(float));
  size_t off_agg  = alloc((size_t)N * 128 * sizeof(float));

  __hip_bfloat16* wz_rad = (__hip_bfloat16*)(ws + off_wzr);
  __hip_bfloat16* wz_e1  = (__hip_bfloat16*)(ws + off_wz1);
  __hip_bfloat16* wz_e2  = (__hip_bfloat16*)(ws + off_wz2);
  __hip_bfloat16* wz_c1  = (__hip_bfloat16*)(ws + off_wzc);
  __hip_bfloat16* wz_n1  = (__hip_bfloat16*)(ws + off_wzn1);
  __hip_bfloat16* wz_n2  = (__hip_bfloat16*)(ws + off_wzn2);
  __hip_bfloat16* wz_c2  = (__hip_bfloat16*)(ws + off_wzc2);
  float* pooled_x   = (float*)(ws + off_px);
  int* chsum        = (int*)(ws + off_cs);
  unsigned* cnt_row = (unsigned*)(ws + off_cntr);
  unsigned* cnt_col = (unsigned*)(ws + off_cntc);
  float* x_acc      = (float*)(ws + off_xacc);
  float* agg        = (float*)(ws + off_agg);

  hipMemsetAsync(ws + off_cntr, 0, off - off_cntr, stream);

  k_wswz<<<dim3((165888 + 255) / 256), dim3(256), 0, stream>>>(
      rad_w, e_w1, e_w2, c_w1, n_w1, n_w2, c_w2,
      wz_rad, wz_e1, wz_e2, wz_c1, wz_n1, wz_n2, wz_c2);
  k_prep<<<dim3((N + 255) / 256), dim3(256), 0, stream>>>(x, cw, pooled_x, chsum, N);
  k_edge<<<dim3((E + TE - 1) / TE), dim3(256), 0, stream>>>(
      h, x, attr, cw, row, col, pooled_x, chsum,
      wz_rad, rad_b, wz_e1, e_b1, wz_e2, e_b2, att_w, att_b,
      wz_c1, c_b1, wz_c2, c_b2, cnt_row, cnt_col, x_acc, agg, E);
  k_node<<<dim3((N + TN - 1) / TN), dim3(256), 0, stream>>>(
      h, agg, cnt_col, wz_n1, n_b1, wz_n2, n_b2, ln_g, ln_b, (float*)d_out, N);
  k_xnew<<<dim3((N * 42 + 255) / 256), dim3(256), 0, stream>>>(
      x, x_acc, cnt_row, (float*)d_out + (size_t)N * 128, N);
}

// Round 5
// 419.970 us; speedup vs baseline: 4.1716x; 1.0869x over previous
//
#include <hip/hip_runtime.h>
#include <hip/hip_bf16.h>

// EnhancedGNNEncoder round 5:
//  - attrS[n][a][i] = attr[n][i][a]*cw[n][i] precomputed bf16 (i pad 14->16) in
//    exactly MFMA A/B fragment order -> einsum attr operands are single bf16x8
//    loads (kills per-edge scale+cvt+pack VALU work and 358->100 MB attr fetch).
//  - h_bf16 precomputed -> edge h-staging is a pure int4 copy (no converts).
//  - k_prep folded into k_pack; k_xnew folded into k_node.
// MFMA 16x16x32: A[m=lane&15][k=quad*8+j], B[k=quad*8+j][n=lane&15],
//                D col=lane&15, row=quad*4+reg.

#define TE 16
#define TN 16
#define PAD 40

typedef __attribute__((ext_vector_type(8))) short bf16x8;
typedef __attribute__((ext_vector_type(4))) float f32x4;

__device__ __forceinline__ float siluf(float v) { return v / (1.f + __expf(-v)); }
__device__ __forceinline__ float sigmf(float v) { return 1.f / (1.f + __expf(-v)); }
__device__ __forceinline__ short f2bs(float f) {
  union { __hip_bfloat16 b; short s; } u;
  u.b = __float2bfloat16(f);
  return u.s;
}

// ---- weight swizzle: fp32 [K][N] -> bf16 B-frag [K/32][N][32] ----
__global__ __launch_bounds__(256) void k_wswz(
    const float* __restrict__ rad_w, const float* __restrict__ e_w1,
    const float* __restrict__ e_w2, const float* __restrict__ c_w1,
    const float* __restrict__ n_w1, const float* __restrict__ n_w2,
    const float* __restrict__ c_w2,
    __hip_bfloat16* __restrict__ wz_rad, __hip_bfloat16* __restrict__ wz_e1,
    __hip_bfloat16* __restrict__ wz_e2, __hip_bfloat16* __restrict__ wz_c1,
    __hip_bfloat16* __restrict__ wz_n1, __hip_bfloat16* __restrict__ wz_n2,
    __hip_bfloat16* __restrict__ wz_c2) {
  int i = blockIdx.x * 256 + threadIdx.x;
  if (i >= 165888) return;
  if (i >= 163840) {  // c_w2: [128][14] -> [4][16][32], n=14,15 zero
    int base = i - 163840;
    int k = base >> 4, n = base & 15;
    wz_c2[(size_t)(k >> 5) * 512 + n * 32 + (k & 31)] =
        (n < 14) ? __float2bfloat16(c_w2[k * 14 + n]) : __float2bfloat16(0.f);
    return;
  }
  const float* W;
  __hip_bfloat16* O;
  int base;
  if (i < 32768) { W = rad_w; O = wz_rad; base = i; }
  else if (i < 81920) { W = e_w1; O = wz_e1; base = i - 32768; }
  else if (i < 98304) { W = e_w2; O = wz_e2; base = i - 81920; }
  else if (i < 114688) { W = c_w1; O = wz_c1; base = i - 98304; }
  else if (i < 147456) { W = n_w1; O = wz_n1; base = i - 114688; }
  else { W = n_w2; O = wz_n2; base = i - 147456; }
  int k = base >> 7, n = base & 127;
  O[(size_t)((k >> 5) * 128 + n) * 32 + (k & 31)] = __float2bfloat16(W[base]);
}

// ---- pack: attrS + h_bf16 + per-node prep (chsum, pooled_x) ----
__global__ __launch_bounds__(256) void k_pack(
    const float* __restrict__ h, const float* __restrict__ x,
    const float* __restrict__ attr, const float* __restrict__ cw,
    __hip_bfloat16* __restrict__ attrS, __hip_bfloat16* __restrict__ hb,
    float* __restrict__ pooled_x, int* __restrict__ chsum, int Nn) {
  int idx = blockIdx.x * 256 + threadIdx.x;
  int na = Nn * 256, nh = Nn * 128;
  if (idx < na) {
    int n = idx >> 8, r = idx & 255, i2 = r >> 4, a = r & 15;
    float v = 0.f;
    if (i2 < 14) v = attr[(size_t)n * 224 + i2 * 16 + a] * cw[(size_t)n * 14 + i2];
    attrS[(size_t)n * 256 + a * 16 + i2] = __float2bfloat16(v);
    return;
  }
  idx -= na;
  if (idx < nh) {
    hb[idx] = __float2bfloat16(h[idx]);
    return;
  }
  idx -= nh;
  if (idx >= Nn) return;
  int n = idx;
  int cnt = 0;
  float sx = 0.f, sy = 0.f, sz = 0.f;
#pragma unroll
  for (int c = 0; c < 14; c++) {
    float w = cw[n * 14 + c];
    if (w != 0.f) {
      cnt++;
      sx += x[n * 42 + c * 3 + 0];
      sy += x[n * 42 + c * 3 + 1];
      sz += x[n * 42 + c * 3 + 2];
    }
  }
  chsum[n] = cnt;
  float inv = 1.f / (float)(cnt > 0 ? cnt : 1);
  pooled_x[n * 3 + 0] = sx * inv;
  pooled_x[n * 3 + 1] = sy * inv;
  pooled_x[n * 3 + 2] = sz * inv;
}

// ---- merged: radial einsum + rad GEMM + edge MLP + gate + roller + scatters ----
__global__ __launch_bounds__(256, 4) void k_edge(
    const __hip_bfloat16* __restrict__ hb, const float* __restrict__ x,
    const __hip_bfloat16* __restrict__ attrS,
    const int* __restrict__ row, const int* __restrict__ col,
    const float* __restrict__ pooled_x, const int* __restrict__ chsum,
    const __hip_bfloat16* __restrict__ wz_rad, const float* __restrict__ rad_b,
    const __hip_bfloat16* __restrict__ wz_e1, const float* __restrict__ e_b1,
    const __hip_bfloat16* __restrict__ wz_e2, const float* __restrict__ e_b2,
    const float* __restrict__ att_w, const float* __restrict__ att_b,
    const __hip_bfloat16* __restrict__ wz_c1, const float* __restrict__ c_b1,
    const __hip_bfloat16* __restrict__ wz_c2, const float* __restrict__ c_b2,
    unsigned* __restrict__ cnt_row, unsigned* __restrict__ cnt_col,
    float* __restrict__ x_acc, float* __restrict__ agg, int Ee) {
  __shared__ __hip_bfloat16 sA[12][16][PAD];  // [h_row | h_col | radf] K=384
  __shared__ __hip_bfloat16 sW[8][16][PAD];   // sRad / later sT(0..3),sU(4..7),sV(0..3)
  __shared__ float s_xr[TE][42];
  __shared__ float s_pc[TE][3];
  __shared__ float s_cm[TE][14];
  __shared__ float s_pool[TE][14];
  __shared__ float s_att[TE], s_rn[TE];
  __shared__ int s_row[TE], s_col[TE], s_cs[TE];

  const int t = threadIdx.x;
  const int e0 = blockIdx.x * TE;
  const int ne = min(TE, Ee - e0);

  if (t < TE) {
    int e = e0 + min(t, ne - 1);
    s_row[t] = row[e];
    s_col[t] = col[e];
    s_cs[t] = chsum[s_row[t]];
    if (t < ne) {
      atomicAdd(&cnt_row[s_row[t]], 1u);
      atomicAdd(&cnt_col[s_col[t]], 1u);
    }
  }
  __syncthreads();

  // h staging -> sA[0..7]: pure bf16 int4 copy (no converts)
  for (int i = t; i < TE * 32; i += 256) {
    int half = i >> 8;                  // 0: row-h, 1: col-h
    int m = (i >> 4) & 15, c8 = i & 15;
    int kb = (c8 >> 2) + half * 4, kk = (c8 & 3) * 8;
    int node = half ? s_col[m] : s_row[m];
    *(int4*)&sA[kb][m][kk] = *(const int4*)&hb[(size_t)node * 128 + c8 * 8];
  }
  if (t < TE * 3) {
    int e = t / 3, d = t % 3;
    s_pc[e][d] = pooled_x[(size_t)s_col[e] * 3 + d];
  }

  const int lane = t & 63, wave = t >> 6, quad = lane >> 4, mr = lane & 15;

  // ---- einsum: each wave owns 4 edges ----
  f32x4 zacc = {0.f, 0.f, 0.f, 0.f};
  const bf16x8 zero8 = {0, 0, 0, 0, 0, 0, 0, 0};
#pragma unroll
  for (int p = 0; p < 4; p++) {
    const int e = wave * 4 + p;
    const int re = s_row[e], ce = s_col[e];
    // attr operands: direct fragment-order bf16 loads (quads 2,3 are K-pad)
    bf16x8 bC = zero8, aR = zero8;
    if (quad < 2) {
      bC = *(const bf16x8*)&attrS[(size_t)ce * 256 + mr * 16 + quad * 8];
      aR = *(const bf16x8*)&attrS[(size_t)re * 256 + mr * 16 + quad * 8];
    }
    float xr0 = 0.f, xr1 = 0.f, xr2 = 0.f, xc0 = 0.f, xc1 = 0.f, xc2 = 0.f;
    if (mr < 14) {
      const float* xp = x + (size_t)re * 42 + mr * 3;
      xr0 = xp[0]; xr1 = xp[1]; xr2 = xp[2];
      const float* xq = x + (size_t)ce * 42 + mr * 3;
      xc0 = xq[0]; xc1 = xq[1]; xc2 = xq[2];
    }
    if (quad == 0 && mr < 14) {
      s_xr[e][mr * 3 + 0] = xr0;
      s_xr[e][mr * 3 + 1] = xr1;
      s_xr[e][mr * 3 + 2] = xr2;
    }
    bf16x8 aD;
#pragma unroll
    for (int j = 0; j < 8; j++) {
      const int k = quad * 8 + j;
      float bx = __shfl(xc0, k), by = __shfl(xc1, k), bz = __shfl(xc2, k);
      float dx = xr0 - bx, dy = xr1 - by, dz = xr2 - bz;
      float dist = (k < 14 && mr < 14) ? sqrtf(dx * dx + dy * dy + dz * dz) : 0.f;
      aD[j] = f2bs(dist);
    }
    f32x4 m1 = __builtin_amdgcn_mfma_f32_16x16x32_bf16(aD, bC, zacc, 0, 0, 0);
    bf16x8 bM;
#pragma unroll
    for (int j = 0; j < 8; j++) {
      const int qs = (quad * 2 + (j >> 2)) & 3;   // wraps for quad>=2 (masked)
      float mv = __shfl(m1[j & 3], (qs << 4) | mr);
      if (quad >= 2) mv = 0.f;                    // M1 rows >=16 are zero-pad
      bM[j] = f2bs(mv);
    }
    f32x4 rd = __builtin_amdgcn_mfma_f32_16x16x32_bf16(aR, bM, zacc, 0, 0, 0);
    float ss = rd[0] * rd[0] + rd[1] * rd[1] + rd[2] * rd[2] + rd[3] * rd[3];
    ss += __shfl_xor(ss, 32); ss += __shfl_xor(ss, 16); ss += __shfl_xor(ss, 8);
    ss += __shfl_xor(ss, 4);  ss += __shfl_xor(ss, 2);  ss += __shfl_xor(ss, 1);
    if (lane == 0) s_rn[e] = sqrtf(ss) + 1.0f;
#pragma unroll
    for (int r = 0; r < 4; r++) {
      const int aa = quad * 4 + r;                // radial row a
      sW[aa >> 1][e][((aa & 1) << 4) | mr] = __float2bfloat16(rd[r]);
    }
  }
  __syncthreads();

  const int n0 = wave * 32;
  // ---- rad GEMM: radf = (radial @ rad_w + rad_b)/rn -> sA[8..11] ----
  {
    f32x4 acc0 = zacc, acc1 = zacc;
#pragma unroll
    for (int kb = 0; kb < 8; kb++) {
      bf16x8 a = *(const bf16x8*)&sW[kb][mr][quad * 8];
      const __hip_bfloat16* wp = wz_rad + ((size_t)(kb * 128 + n0 + mr) * 32 + quad * 8);
      bf16x8 b0 = *(const bf16x8*)wp;
      bf16x8 b1 = *(const bf16x8*)(wp + 16 * 32);
      acc0 = __builtin_amdgcn_mfma_f32_16x16x32_bf16(a, b0, acc0, 0, 0, 0);
      acc1 = __builtin_amdgcn_mfma_f32_16x16x32_bf16(a, b1, acc1, 0, 0, 0);
    }
    float bias0 = rad_b[n0 + mr], bias1 = rad_b[n0 + 16 + mr];
#pragma unroll
    for (int r = 0; r < 4; r++) {
      int e = quad * 4 + r;
      float inv = 1.f / s_rn[e];
      sA[8 + wave][e][mr]      = __float2bfloat16((acc0[r] + bias0) * inv);
      sA[8 + wave][e][16 + mr] = __float2bfloat16((acc1[r] + bias1) * inv);
    }
  }
  __syncthreads();
  // ---- stage 1: ef1 = silu(A @ e_w1 + e_b1), K=384 -> sT (=sW[0..3]) ----
  {
    f32x4 acc0 = zacc, acc1 = zacc;
#pragma unroll
    for (int kb = 0; kb < 12; kb++) {
      bf16x8 a = *(const bf16x8*)&sA[kb][mr][quad * 8];
      const __hip_bfloat16* wp = wz_e1 + ((size_t)(kb * 128 + n0 + mr) * 32 + quad * 8);
      bf16x8 b0 = *(const bf16x8*)wp;
      bf16x8 b1 = *(const bf16x8*)(wp + 16 * 32);
      acc0 = __builtin_amdgcn_mfma_f32_16x16x32_bf16(a, b0, acc0, 0, 0, 0);
      acc1 = __builtin_amdgcn_mfma_f32_16x16x32_bf16(a, b1, acc1, 0, 0, 0);
    }
    float bias0 = e_b1[n0 + mr], bias1 = e_b1[n0 + 16 + mr];
#pragma unroll
    for (int r = 0; r < 4; r++) {
      int e = quad * 4 + r;
      sW[wave][e][mr]      = __float2bfloat16(siluf(acc0[r] + bias0));
      sW[wave][e][16 + mr] = __float2bfloat16(siluf(acc1[r] + bias1));
    }
  }
  __syncthreads();
  // ---- stage 2: ef2 = silu(ef1 @ e_w2 + e_b2) -> sU (=sW[4..7]) ----
  {
    f32x4 acc0 = zacc, acc1 = zacc;
#pragma unroll
    for (int kb = 0; kb < 4; kb++) {
      bf16x8 a = *(const bf16x8*)&sW[kb][mr][quad * 8];
      const __hip_bfloat16* wp = wz_e2 + ((size_t)(kb * 128 + n0 + mr) * 32 + quad * 8);
      bf16x8 b0 = *(const bf16x8*)wp;
      bf16x8 b1 = *(const bf16x8*)(wp + 16 * 32);
      acc0 = __builtin_amdgcn_mfma_f32_16x16x32_bf16(a, b0, acc0, 0, 0, 0);
      acc1 = __builtin_amdgcn_mfma_f32_16x16x32_bf16(a, b1, acc1, 0, 0, 0);
    }
    float bias0 = e_b2[n0 + mr], bias1 = e_b2[n0 + 16 + mr];
#pragma unroll
    for (int r = 0; r < 4; r++) {
      int e = quad * 4 + r;
      sW[4 + wave][e][mr]      = __float2bfloat16(siluf(acc0[r] + bias0));
      sW[4 + wave][e][16 + mr] = __float2bfloat16(siluf(acc1[r] + bias1));
    }
  }
  __syncthreads();
  // ---- attention gate: in-wave shfl reduction ----
  {
    int e = t >> 4, p = t & 15;
    float s = 0.f;
#pragma unroll
    for (int j = 0; j < 8; j++) {
      int k = p * 8 + j;
      s += __bfloat162float(sW[4 + (k >> 5)][e][k & 31]) * att_w[k];
    }
    s += __shfl_xor(s, 8); s += __shfl_xor(s, 4);
    s += __shfl_xor(s, 2); s += __shfl_xor(s, 1);
    if (p == 0) s_att[e] = sigmf(s + att_b[0]);
  }
  __syncthreads();
  // ---- stage 3: cmh = silu(att*(ef2 @ c_w1) + c_b1) -> sV (=sW[0..3]) ----
  {
    f32x4 acc0 = zacc, acc1 = zacc;
#pragma unroll
    for (int kb = 0; kb < 4; kb++) {
      bf16x8 a = *(const bf16x8*)&sW[4 + kb][mr][quad * 8];
      const __hip_bfloat16* wp = wz_c1 + ((size_t)(kb * 128 + n0 + mr) * 32 + quad * 8);
      bf16x8 b0 = *(const bf16x8*)wp;
      bf16x8 b1 = *(const bf16x8*)(wp + 16 * 32);
      acc0 = __builtin_amdgcn_mfma_f32_16x16x32_bf16(a, b0, acc0, 0, 0, 0);
      acc1 = __builtin_amdgcn_mfma_f32_16x16x32_bf16(a, b1, acc1, 0, 0, 0);
    }
    float bias0 = c_b1[n0 + mr], bias1 = c_b1[n0 + 16 + mr];
#pragma unroll
    for (int r = 0; r < 4; r++) {
      int e = quad * 4 + r;
      float av = s_att[e];
      sW[wave][e][mr]      = __float2bfloat16(siluf(av * acc0[r] + bias0));
      sW[wave][e][16 + mr] = __float2bfloat16(siluf(av * acc1[r] + bias1));
    }
  }
  __syncthreads();
  // ---- cm = cmh @ c_w2 + c_b2 via MFMA (wave 0 only) ----
  if (wave == 0) {
    f32x4 acc = zacc;
#pragma unroll
    for (int kb = 0; kb < 4; kb++) {
      bf16x8 a = *(const bf16x8*)&sW[kb][mr][quad * 8];
      bf16x8 b = *(const bf16x8*)(wz_c2 + ((size_t)(kb * 16 + mr) * 32 + quad * 8));
      acc = __builtin_amdgcn_mfma_f32_16x16x32_bf16(a, b, acc, 0, 0, 0);
    }
    if (mr < 14) {
      float bias = c_b2[mr];
#pragma unroll
      for (int r = 0; r < 4; r++) s_cm[quad * 4 + r][mr] = acc[r] + bias;
    }
  }
  __syncthreads();
  // ---- RollerPooling ----
  if (t < TE * 14) {
    int e = t / 14, c = t % 14;
    int wsz = 15 - s_cs[e];
    int hi = min(c + wsz, 14);
    float s = 0.f;
    for (int j = c; j < hi; j++) s += s_cm[e][j];
    s_pool[e][c] = s / (float)wsz;
  }
  __syncthreads();
  // ---- trans scatter ----
  for (int i = t; i < TE * 42; i += 256) {
    int e = i / 42, r = i % 42, c = r / 3, d = r % 3;
    if (e < ne) {
      float v = (s_xr[e][r] - s_pc[e][d]) * s_pool[e][c];
      unsafeAtomicAdd(&x_acc[(size_t)s_row[e] * 42 + r], v);
    }
  }
  // ---- agg scatter (gated ef2) ----
  for (int i = t; i < TE * 128; i += 256) {
    int e = i >> 7, o = i & 127;
    if (e < ne) {
      float v = __bfloat162float(sW[4 + (o >> 5)][e][o & 31]) * s_att[e];
      unsafeAtomicAdd(&agg[(size_t)s_col[e] * 128 + o], v);
    }
  }
}

// ---- node MLP (MFMA) + residual + LayerNorm + fused x_new ----
__global__ __launch_bounds__(256) void k_node(
    const float* __restrict__ h, const float* __restrict__ agg,
    const unsigned* __restrict__ cnt_col,
    const __hip_bfloat16* __restrict__ wz_n1, const float* __restrict__ n_b1,
    const __hip_bfloat16* __restrict__ wz_n2, const float* __restrict__ n_b2,
    const float* __restrict__ ln_g, const float* __restrict__ ln_b,
    const float* __restrict__ x, const float* __restrict__ x_acc,
    const unsigned* __restrict__ cnt_row,
    float* __restrict__ out_h, float* __restrict__ out_x, int Nn) {
  __shared__ __hip_bfloat16 sA[8][16][PAD];
  __shared__ __hip_bfloat16 sT[4][16][PAD];
  __shared__ float s_h[TN][128];
  __shared__ float s_o[TN][132];
  __shared__ float s_red[TN][16], s_mu[TN], s_rs[TN];
  const int t = threadIdx.x;
  const int nb0 = blockIdx.x * TN;
  const int nn = min(TN, Nn - nb0);

  // fused x_new (independent of LN pipeline; issue early)
  for (int i = t; i < TN * 42; i += 256) {
    int n = i / 42, r = i % 42;
    if (n < nn) {
      size_t gi = (size_t)(nb0 + n) * 42 + r;
      unsigned c = cnt_row[nb0 + n];
      out_x[gi] = x[gi] + x_acc[gi] / (float)(c > 0 ? c : 1);
    }
  }

  for (int i = t; i < TN * 64; i += 256) {
    int m = i >> 6, kp = (i & 63) << 1;
    int kb = kp >> 5, kk = kp & 31;
    int gn = nb0 + min(m, nn - 1);
    const float2 hv = *(const float2*)&h[(size_t)gn * 128 + kp];
    sA[kb][m][kk]     = __float2bfloat16(hv.x);
    sA[kb][m][kk + 1] = __float2bfloat16(hv.y);
    s_h[m][kp]     = hv.x;
    s_h[m][kp + 1] = hv.y;
    unsigned c = cnt_col[gn];
    float inv = 1.f / (float)(c > 0 ? c : 1);
    const float2 gv = *(const float2*)&agg[(size_t)gn * 128 + kp];
    sA[4 + kb][m][kk]     = __float2bfloat16(gv.x * inv);
    sA[4 + kb][m][kk + 1] = __float2bfloat16(gv.y * inv);
  }
  __syncthreads();
  const int lane = t & 63, wave = t >> 6, quad = lane >> 4, mr = lane & 15;
  const int n0 = wave * 32;
  f32x4 zacc = {0.f, 0.f, 0.f, 0.f};
  {
    f32x4 acc0 = zacc, acc1 = zacc;
#pragma unroll
    for (int kb = 0; kb < 8; kb++) {
      bf16x8 a = *(const bf16x8*)&sA[kb][mr][quad * 8];
      const __hip_bfloat16* wp = wz_n1 + ((size_t)(kb * 128 + n0 + mr) * 32 + quad * 8);
      bf16x8 b0 = *(const bf16x8*)wp;
      bf16x8 b1 = *(const bf16x8*)(wp + 16 * 32);
      acc0 = __builtin_amdgcn_mfma_f32_16x16x32_bf16(a, b0, acc0, 0, 0, 0);
      acc1 = __builtin_amdgcn_mfma_f32_16x16x32_bf16(a, b1, acc1, 0, 0, 0);
    }
    float bias0 = n_b1[n0 + mr], bias1 = n_b1[n0 + 16 + mr];
#pragma unroll
    for (int r = 0; r < 4; r++) {
      int m = quad * 4 + r;
      sT[wave][m][mr]      = __float2bfloat16(siluf(acc0[r] + bias0));
      sT[wave][m][16 + mr] = __float2bfloat16(siluf(acc1[r] + bias1));
    }
  }
  __syncthreads();
  {
    f32x4 acc0 = zacc, acc1 = zacc;
#pragma unroll
    for (int kb = 0; kb < 4; kb++) {
      bf16x8 a = *(const bf16x8*)&sT[kb][mr][quad * 8];
      const __hip_bfloat16* wp = wz_n2 + ((size_t)(kb * 128 + n0 + mr) * 32 + quad * 8);
      bf16x8 b0 = *(const bf16x8*)wp;
      bf16x8 b1 = *(const bf16x8*)(wp + 16 * 32);
      acc0 = __builtin_amdgcn_mfma_f32_16x16x32_bf16(a, b0, acc0, 0, 0, 0);
      acc1 = __builtin_amdgcn_mfma_f32_16x16x32_bf16(a, b1, acc1, 0, 0, 0);
    }
    float bias0 = n_b2[n0 + mr], bias1 = n_b2[n0 + 16 + mr];
#pragma unroll
    for (int r = 0; r < 4; r++) {
      int m = quad * 4 + r;
      s_o[m][n0 + mr]      = s_h[m][n0 + mr] + acc0[r] + bias0;
      s_o[m][n0 + 16 + mr] = s_h[m][n0 + 16 + mr] + acc1[r] + bias1;
    }
  }
  __syncthreads();
  {
    int n = t >> 4, p = t & 15;
    float s = 0.f;
#pragma unroll
    for (int j = 0; j < 8; j++) s += s_o[n][p * 8 + j];
    s_red[n][p] = s;
  }
  __syncthreads();
  if (t < TN) {
    float s = 0.f;
#pragma unroll
    for (int i = 0; i < 16; i++) s += s_red[t][i];
    s_mu[t] = s * (1.f / 128.f);
  }
  __syncthreads();
  {
    int n = t >> 4, p = t & 15;
    float mu = s_mu[n], s = 0.f;
#pragma unroll
    for (int j = 0; j < 8; j++) {
      float d = s_o[n][p * 8 + j] - mu;
      s += d * d;
    }
    s_red[n][p] = s;
  }
  __syncthreads();
  if (t < TN) {
    float s = 0.f;
#pragma unroll
    for (int i = 0; i < 16; i++) s += s_red[t][i];
    s_rs[t] = rsqrtf(s * (1.f / 128.f) + 1e-5f);
  }
  __syncthreads();
  for (int i = t; i < TN * 128; i += 256) {
    int n = i >> 7, k = i & 127;
    if (n < nn)
      out_h[(size_t)(nb0 + n) * 128 + k] = (s_o[n][k] - s_mu[n]) * s_rs[n] * ln_g[k] + ln_b[k];
  }
}

extern "C" void kernel_launch(void* const* d_in, const int* in_sizes, int n_in,
                              void* d_out, int out_size, void* d_ws, size_t ws_size,
                              hipStream_t stream) {
  const float* h     = (const float*)d_in[0];
  const float* x     = (const float*)d_in[1];
  const float* attr  = (const float*)d_in[2];
  const float* cw    = (const float*)d_in[3];
  const int*   row   = (const int*)d_in[4];
  const int*   col   = (const int*)d_in[5];
  const float* rad_w = (const float*)d_in[6];
  const float* rad_b = (const float*)d_in[7];
  const float* e_w1  = (const float*)d_in[8];
  const float* e_b1  = (const float*)d_in[9];
  const float* e_w2  = (const float*)d_in[10];
  const float* e_b2  = (const float*)d_in[11];
  const float* att_w = (const float*)d_in[12];
  const float* att_b = (const float*)d_in[13];
  const float* c_w1  = (const float*)d_in[14];
  const float* c_b1  = (const float*)d_in[15];
  const float* c_w2  = (const float*)d_in[16];
  const float* c_b2  = (const float*)d_in[17];
  const float* n_w1  = (const float*)d_in[18];
  const float* n_b1  = (const float*)d_in[19];
  const float* n_w2  = (const float*)d_in[20];
  const float* n_b2  = (const float*)d_in[21];
  const float* ln_g  = (const float*)d_in[22];
  const float* ln_b  = (const float*)d_in[23];

  const int N = in_sizes[0] / 128;
  const int E = in_sizes[4];

  char* ws = (char*)d_ws;
  size_t off = 0;
  auto alloc = [&](size_t bytes) {
    size_t o = off;
    off += (bytes + 255) & ~(size_t)255;
    return o;
  };
  size_t off_wzr  = alloc(32768 * sizeof(__hip_bfloat16));
  size_t off_wz1  = alloc(49152 * sizeof(__hip_bfloat16));
  size_t off_wz2  = alloc(16384 * sizeof(__hip_bfloat16));
  size_t off_wzc  = alloc(16384 * sizeof(__hip_bfloat16));
  size_t off_wzn1 = alloc(32768 * sizeof(__hip_bfloat16));
  size_t off_wzn2 = alloc(16384 * sizeof(__hip_bfloat16));
  size_t off_wzc2 = alloc(2048 * sizeof(__hip_bfloat16));
  size_t off_atS  = alloc((size_t)N * 256 * sizeof(__hip_bfloat16));
  size_t off_hb   = alloc((size_t)N * 128 * sizeof(__hip_bfloat16));
  size_t off_px   = alloc((size_t)N * 3 * sizeof(float));
  size_t off_cs   = alloc((size_t)N * sizeof(int));
  size_t off_cntr = alloc((size_t)N * sizeof(unsigned));
  size_t off_cntc = alloc((size_t)N * sizeof(unsigned));
  size_t off_xacc = alloc((size_t)N * 42 * sizeof(float));
  size_t off_agg  = alloc((size_t)N * 128 * sizeof(float));

  __hip_bfloat16* wz_rad = (__hip_bfloat16*)(ws + off_wzr);
  __hip_bfloat16* wz_e1  = (__hip_bfloat16*)(ws + off_wz1);
  __hip_bfloat16* wz_e2  = (__hip_bfloat16*)(ws + off_wz2);
  __hip_bfloat16* wz_c1  = (__hip_bfloat16*)(ws + off_wzc);
  __hip_bfloat16* wz_n1  = (__hip_bfloat16*)(ws + off_wzn1);
  __hip_bfloat16* wz_n2  = (__hip_bfloat16*)(ws + off_wzn2);
  __hip_bfloat16* wz_c2  = (__hip_bfloat16*)(ws + off_wzc2);
  __hip_bfloat16* attrS  = (__hip_bfloat16*)(ws + off_atS);
  __hip_bfloat16* hb     = (__hip_bfloat16*)(ws + off_hb);
  float* pooled_x   = (float*)(ws + off_px);
  int* chsum        = (int*)(ws + off_cs);
  unsigned* cnt_row = (unsigned*)(ws + off_cntr);
  unsigned* cnt_col = (unsigned*)(ws + off_cntc);
  float* x_acc      = (float*)(ws + off_xacc);
  float* agg        = (float*)(ws + off_agg);

  hipMemsetAsync(ws + off_cntr, 0, off - off_cntr, stream);

  k_wswz<<<dim3((165888 + 255) / 256), dim3(256), 0, stream>>>(
      rad_w, e_w1, e_w2, c_w1, n_w1, n_w2, c_w2,
      wz_rad, wz_e1, wz_e2, wz_c1, wz_n1, wz_n2, wz_c2);
  k_pack<<<dim3((N * 385 + 255) / 256), dim3(256), 0, stream>>>(
      h, x, attr, cw, attrS, hb, pooled_x, chsum, N);
  k_edge<<<dim3((E + TE - 1) / TE), dim3(256), 0, stream>>>(
      hb, x, attrS, row, col, pooled_x, chsum,
      wz_rad, rad_b, wz_e1, e_b1, wz_e2, e_b2, att_w, att_b,
      wz_c1, c_b1, wz_c2, c_b2, cnt_row, cnt_col, x_acc, agg, E);
  k_node<<<dim3((N + TN - 1) / TN), dim3(256), 0, stream>>>(
      h, agg, cnt_col, wz_n1, n_b1, wz_n2, n_b2, ln_g, ln_b,
      x, x_acc, cnt_row, (float*)d_out, (float*)d_out + (size_t)N * 128, N);
}